// Round 8
// baseline (4622.705 us; speedup 1.0000x reference)
//
#include <hip/hip_runtime.h>
#include <math.h>

// Problem constants (GridSmoother)
#define B_   16
#define P_   8192
#define N_   1024
#define D_   384
#define L_   12
#define H_   6
#define HD_  64
#define M_   (B_*N_)     // 16384 rows
#define DQKV_ (3*D_)     // 1152
#define DH_   (4*D_)     // 1536

typedef unsigned short ushort_t;
typedef unsigned long long u64_t;
typedef __attribute__((ext_vector_type(8))) short short8;
typedef __attribute__((ext_vector_type(4))) float floatx4;
typedef __attribute__((ext_vector_type(2))) float floatx2;

// bf16 helpers (RNE), raw-bits representation
__device__ __forceinline__ ushort_t f2bf(float f) {
    unsigned u = __float_as_uint(f);
    unsigned rounding = 0x7fffu + ((u >> 16) & 1u);
    return (ushort_t)((u + rounding) >> 16);
}
__device__ __forceinline__ float bf2f(ushort_t u) {
    return __uint_as_float(((unsigned)u) << 16);
}

// ---------------------------------------------------------------------------
// Embed: X[m,d] = sum_k grid[m,k] * ew[k,d]   (K=3)
__global__ __launch_bounds__(D_) void embed_kernel(const float* __restrict__ g,
                                                   const float* __restrict__ ew,
                                                   float* __restrict__ X) {
    int m = blockIdx.x;
    int d = threadIdx.x;
    float g0 = g[m*3+0], g1 = g[m*3+1], g2 = g[m*3+2];
    X[(size_t)m*D_ + d] = g0*ew[0*D_+d] + g1*ew[1*D_+d] + g2*ew[2*D_+d];
}

// ---------------------------------------------------------------------------
// Weight transpose-cast: W [L][K][N] f32 -> Wt [L][N][K] bf16 bits
__global__ __launch_bounds__(256) void transcast_kernel(const float* __restrict__ W,
                                                        ushort_t* __restrict__ Wt,
                                                        int K, int Nc) {
    __shared__ float t[32][33];
    const float* Wl = W + (size_t)blockIdx.z*K*Nc;
    ushort_t* Wtl = Wt + (size_t)blockIdx.z*K*Nc;
    int n0 = blockIdx.x*32, k0 = blockIdx.y*32;
    int tx = threadIdx.x & 31, ty = threadIdx.x >> 5;   // 32 x 8
#pragma unroll
    for (int j = 0; j < 32; j += 8)
        t[ty+j][tx] = Wl[(size_t)(k0+ty+j)*Nc + n0+tx];
    __syncthreads();
#pragma unroll
    for (int j = 0; j < 32; j += 8)
        Wtl[(size_t)(n0+ty+j)*K + k0+tx] = f2bf(t[tx][ty+j]);
}

// ---------------------------------------------------------------------------
// LayerNorm: one wave per row of 384; reads f32 X, writes bf16 bits.
__global__ __launch_bounds__(256) void ln_kernel(const float* __restrict__ Xin,
                                                 const float* __restrict__ w,
                                                 const float* __restrict__ bvec,
                                                 ushort_t* __restrict__ out) {
    int wid = threadIdx.x >> 6, lane = threadIdx.x & 63;
    int row = blockIdx.x*4 + wid;
    const float* xr = Xin + (size_t)row*D_;
    float v[6];
#pragma unroll
    for (int i = 0; i < 6; i++) v[i] = xr[lane + i*64];
    float s = 0.f;
#pragma unroll
    for (int i = 0; i < 6; i++) s += v[i];
#pragma unroll
    for (int off = 32; off; off >>= 1) s += __shfl_xor(s, off, 64);
    float mean = s * (1.0f/(float)D_);
    float vs = 0.f;
#pragma unroll
    for (int i = 0; i < 6; i++) { float d = v[i]-mean; vs += d*d; }
#pragma unroll
    for (int off = 32; off; off >>= 1) vs += __shfl_xor(vs, off, 64);
    float var = vs * (1.0f/(float)D_);
    float rstd = 1.0f / sqrtf(var + 1e-5f);
    ushort_t* orow = out + (size_t)row*D_;
#pragma unroll
    for (int i = 0; i < 6; i++) {
        int e = lane + i*64;
        orow[e] = f2bf((v[i]-mean)*rstd*w[e] + bvec[e]);
    }
}

// ---------------------------------------------------------------------------
__device__ __forceinline__ float gelu_f(float x) {
    const float c = 0.7978845608028654f;   // sqrt(2/pi)
    float x3 = x*x*x;
    return 0.5f*x*(1.0f + tanhf(c*(x + 0.044715f*x3)));
}

// ---------------------------------------------------------------------------
// MFMA bf16 GEMM v2 (R5 configuration — LDS stride 32, 16B-aligned b128):
// register-prefetch staging, vectorized epilogues.
// EPI: 0 = bias -> bf16 out; 1 = bias + residual add into f32 C;
//      2 = gelu(bias+acc) -> bf16 out;
//      3 = QKV split: cols<768 packed bf16, cols>=768 scatter to VT.
template<int EPI>
__global__ __launch_bounds__(256) void mfma_gemm(const ushort_t* __restrict__ A,
                                                 const ushort_t* __restrict__ Wt,
                                                 const float* __restrict__ bias,
                                                 void* __restrict__ Cout,
                                                 ushort_t* __restrict__ VT,
                                                 int K, int Nc) {
    __shared__ __attribute__((aligned(16))) ushort_t smem[2*128*32];   // 16 KB
    ushort_t* smA = smem;
    ushort_t* smB = smem + 128*32;
    int tid = threadIdx.x;
    int lane = tid & 63, w = tid >> 6;
    int wm = w >> 1, wn = w & 1;
    int L = lane & 15, G = lane >> 4;
    int rowBase = blockIdx.y * 128, colBase = blockIdx.x * 128;

    floatx4 acc[4][4];
#pragma unroll
    for (int i = 0; i < 4; i++)
#pragma unroll
        for (int j = 0; j < 4; j++) acc[i][j] = (floatx4){0.f,0.f,0.f,0.f};

    // staging map: 256 threads x 2 chunks per buffer; chunk = 16B = 8 bf16
    int sr = tid >> 2;          // row 0..63 (and +64)
    int kc = tid & 3;           // k-chunk 0..3
    const ushort_t* Ag = A  + (size_t)(rowBase + sr)*K + kc*8;
    const ushort_t* Bg = Wt + (size_t)(colBase + sr)*K + kc*8;
    size_t step64 = (size_t)64*K;

    short8 ra0, ra1, rb0, rb1;
    ra0 = *(const short8*)(Ag);
    ra1 = *(const short8*)(Ag + step64);
    rb0 = *(const short8*)(Bg);
    rb1 = *(const short8*)(Bg + step64);

    for (int k0 = 0; k0 < K; k0 += 32) {
        __syncthreads();
        *(short8*)(smA + sr*32 + kc*8)        = ra0;
        *(short8*)(smA + (64+sr)*32 + kc*8)   = ra1;
        *(short8*)(smB + sr*32 + kc*8)        = rb0;
        *(short8*)(smB + (64+sr)*32 + kc*8)   = rb1;
        __syncthreads();
        if (k0 + 32 < K) {      // prefetch next k-slab; loads stay in flight
            ra0 = *(const short8*)(Ag + k0 + 32);
            ra1 = *(const short8*)(Ag + step64 + k0 + 32);
            rb0 = *(const short8*)(Bg + k0 + 32);
            rb1 = *(const short8*)(Bg + step64 + k0 + 32);
        }
        short8 af[4], bfr[4];
#pragma unroll
        for (int t = 0; t < 4; t++) {
            af[t]  = *(const short8*)(smA + (wm*64 + t*16 + L)*32 + G*8);
            bfr[t] = *(const short8*)(smB + (wn*64 + t*16 + L)*32 + G*8);
        }
#pragma unroll
        for (int mt = 0; mt < 4; mt++)
#pragma unroll
            for (int nt = 0; nt < 4; nt++)
                acc[mt][nt] = __builtin_amdgcn_mfma_f32_16x16x32_bf16(
                    af[mt], bfr[nt], acc[mt][nt], 0, 0, 0);
        __syncthreads();
    }

    __syncthreads();   // smem reuse for epilogue

    if (EPI == 3 && colBase >= 2*D_) {
        // pure-V column block: scalar scatter into VT[b,h,d,n]
        int cBase = colBase + wn*64 + L;
        int rBase = rowBase + wm*64 + G*4;
#pragma unroll
        for (int nt = 0; nt < 4; nt++) {
            int col = cBase + nt*16;
            float bv = bias[col];
            int hh = (col - 2*D_) >> 6, d = (col - 2*D_) & 63;
#pragma unroll
            for (int mt = 0; mt < 4; mt++) {
#pragma unroll
                for (int r = 0; r < 4; r++) {
                    int row = rBase + mt*16 + r;
                    int b = row >> 10, n = row & 1023;
                    VT[(((size_t)b*H_ + hh)*64 + d)*N_ + n] = f2bf(acc[mt][nt][r] + bv);
                }
            }
        }
    } else if (EPI == 1) {
        // f32 residual add, vectorized via per-wave LDS slab (16x64 f32)
        float* fs = (float*)smem + w*1024;
        int orow = lane >> 2, c4 = lane & 3;
#pragma unroll
        for (int mt = 0; mt < 4; mt++) {
#pragma unroll
            for (int nt = 0; nt < 4; nt++) {
                float bv = bias[colBase + wn*64 + nt*16 + L];
#pragma unroll
                for (int r = 0; r < 4; r++)
                    fs[(G*4+r)*64 + nt*16 + L] = acc[mt][nt][r] + bv;
            }
            float* og = (float*)Cout + (size_t)(rowBase + wm*64 + mt*16 + orow)*Nc
                        + colBase + wn*64;
#pragma unroll
            for (int kk = 0; kk < 4; kk++) {
                float4 sv = *(float4*)(fs + orow*64 + kk*16 + c4*4);
                float4 gv = *(float4*)(og + kk*16 + c4*4);
                gv.x += sv.x; gv.y += sv.y; gv.z += sv.z; gv.w += sv.w;
                *(float4*)(og + kk*16 + c4*4) = gv;
            }
        }
    } else {
        // bf16 out (EPI 0/2/3-QK), vectorized via per-wave LDS slab (stride 72)
        ushort_t* us = smem + w*1152;
        int orow = lane >> 2, oc = lane & 3;
#pragma unroll
        for (int mt = 0; mt < 4; mt++) {
#pragma unroll
            for (int nt = 0; nt < 4; nt++) {
                float bv = bias[colBase + wn*64 + nt*16 + L];
#pragma unroll
                for (int r = 0; r < 4; r++) {
                    float v = acc[mt][nt][r] + bv;
                    if (EPI == 2) v = gelu_f(v);
                    us[(G*4+r)*72 + nt*16 + L] = f2bf(v);
                }
            }
            short8 o0 = *(short8*)(us + orow*72 + oc*8);
            short8 o1 = *(short8*)(us + orow*72 + 32 + oc*8);
            ushort_t* og = (ushort_t*)Cout + (size_t)(rowBase + wm*64 + mt*16 + orow)*Nc
                           + colBase + wn*64;
            *(short8*)(og + oc*8) = o0;
            *(short8*)(og + 32 + oc*8) = o1;
        }
    }
}

// ---------------------------------------------------------------------------
// Flash attention v2 (R5 configuration): 64-key tiles, register-prefetch
// staging, 2 barriers/tile, wave-private P round-trip, vectorized O store.
// LPAD 72 elements = 144 B (16B-aligned for b128).
#define LPAD 72
__global__ __launch_bounds__(256) void fattn_kernel(const ushort_t* __restrict__ QKV,
                                                    const ushort_t* __restrict__ VT,
                                                    ushort_t* __restrict__ O) {
    __shared__ __attribute__((aligned(16))) ushort_t Ks[64*LPAD];
    __shared__ __attribute__((aligned(16))) ushort_t Vs[64*LPAD];
    __shared__ __attribute__((aligned(16))) ushort_t Pw[4*16*LPAD];
    int b = blockIdx.z, h = blockIdx.y;
    int qBase = blockIdx.x * 64;
    int tid = threadIdx.x;
    int lane = tid & 63, w = tid >> 6;
    int L = lane & 15, G = lane >> 4;

    short8 qf[2];
    {
        const ushort_t* qp = QKV + ((size_t)(b*N_ + qBase + w*16 + L))*DQKV_ + h*HD_ + G*8;
        qf[0] = *(const short8*)(qp);
        qf[1] = *(const short8*)(qp + 32);
    }

    floatx4 oacc[4];
#pragma unroll
    for (int nt = 0; nt < 4; nt++) oacc[nt] = (floatx4){0.f,0.f,0.f,0.f};
    float mrow[4], lrow[4];
#pragma unroll
    for (int r = 0; r < 4; r++) { mrow[r] = -3.0e38f; lrow[r] = 0.f; }

    ushort_t* pw = Pw + w*16*LPAD;
    const ushort_t* Kbase = QKV + (size_t)b*N_*DQKV_ + D_ + h*HD_;
    const ushort_t* Vbase = VT + ((size_t)b*H_ + h)*64*N_;

    // staging map: 512 chunks (16B) per buffer; thread covers chunk tid and tid+256
    int srow = tid >> 3;         // 0..31 (and +32)
    int dc   = tid & 7;
    const ushort_t* Kg0 = Kbase + (size_t)srow*DQKV_ + dc*8;
    const ushort_t* Kg1 = Kbase + (size_t)(srow+32)*DQKV_ + dc*8;
    const ushort_t* Vg0 = Vbase + (size_t)srow*N_ + dc*8;       // srow = d-row for V
    const ushort_t* Vg1 = Vbase + (size_t)(srow+32)*N_ + dc*8;

    short8 rk0, rk1, rv0, rv1;
    rk0 = *(const short8*)(Kg0);
    rk1 = *(const short8*)(Kg1);
    rv0 = *(const short8*)(Vg0);
    rv1 = *(const short8*)(Vg1);

    for (int kt = 0; kt < N_/64; kt++) {
        __syncthreads();   // prior tile's PV reads of Ks/Vs complete
        *(short8*)(Ks + srow*LPAD + dc*8)       = rk0;
        *(short8*)(Ks + (srow+32)*LPAD + dc*8)  = rk1;
        *(short8*)(Vs + srow*LPAD + dc*8)       = rv0;
        *(short8*)(Vs + (srow+32)*LPAD + dc*8)  = rv1;
        __syncthreads();
        if (kt + 1 < N_/64) {   // prefetch next tile (in flight across compute)
            rk0 = *(const short8*)(Kg0 + (size_t)(kt+1)*64*DQKV_);
            rk1 = *(const short8*)(Kg1 + (size_t)(kt+1)*64*DQKV_);
            rv0 = *(const short8*)(Vg0 + (kt+1)*64);
            rv1 = *(const short8*)(Vg1 + (kt+1)*64);
        }

        // S = Q K^T  (16 q-rows x 64 keys per wave)
        floatx4 sc[4];
#pragma unroll
        for (int ct = 0; ct < 4; ct++) sc[ct] = (floatx4){0.f,0.f,0.f,0.f};
#pragma unroll
        for (int ks = 0; ks < 2; ks++)
#pragma unroll
            for (int ct = 0; ct < 4; ct++) {
                short8 bf = *(const short8*)(Ks + (ct*16 + L)*LPAD + ks*32 + G*8);
                sc[ct] = __builtin_amdgcn_mfma_f32_16x16x32_bf16(qf[ks], bf, sc[ct], 0, 0, 0);
            }

        // online softmax over this 64-key tile
        float rmax[4], rsum[4];
#pragma unroll
        for (int r = 0; r < 4; r++) {
#pragma unroll
            for (int ct = 0; ct < 4; ct++) sc[ct][r] *= 0.125f;
            rmax[r] = fmaxf(fmaxf(sc[0][r], sc[1][r]), fmaxf(sc[2][r], sc[3][r]));
        }
#pragma unroll
        for (int off = 1; off < 16; off <<= 1)
#pragma unroll
            for (int r = 0; r < 4; r++) rmax[r] = fmaxf(rmax[r], __shfl_xor(rmax[r], off, 64));
        float corr[4];
#pragma unroll
        for (int r = 0; r < 4; r++) {
            float mn = fmaxf(mrow[r], rmax[r]);
            corr[r] = __expf(mrow[r] - mn);
            mrow[r] = mn;
            rsum[r] = 0.f;
#pragma unroll
            for (int ct = 0; ct < 4; ct++) {
                float p = __expf(sc[ct][r] - mn);
                sc[ct][r] = p;
                rsum[r] += p;
            }
        }
#pragma unroll
        for (int off = 1; off < 16; off <<= 1)
#pragma unroll
            for (int r = 0; r < 4; r++) rsum[r] += __shfl_xor(rsum[r], off, 64);
#pragma unroll
        for (int r = 0; r < 4; r++) lrow[r] = lrow[r]*corr[r] + rsum[r];

        // P (C-layout) -> wave-private LDS -> A-layout (in-wave ordering, no barrier)
#pragma unroll
        for (int ct = 0; ct < 4; ct++)
#pragma unroll
            for (int r = 0; r < 4; r++)
                pw[(G*4 + r)*LPAD + ct*16 + L] = f2bf(sc[ct][r]);
#pragma unroll
        for (int nt = 0; nt < 4; nt++)
#pragma unroll
            for (int r = 0; r < 4; r++) oacc[nt][r] *= corr[r];

        // O += P V
#pragma unroll
        for (int ks = 0; ks < 2; ks++) {
            short8 pf = *(const short8*)(pw + L*LPAD + ks*32 + G*8);
#pragma unroll
            for (int nt = 0; nt < 4; nt++) {
                short8 vf = *(const short8*)(Vs + (nt*16 + L)*LPAD + ks*32 + G*8);
                oacc[nt] = __builtin_amdgcn_mfma_f32_16x16x32_bf16(pf, vf, oacc[nt], 0, 0, 0);
            }
        }
    }

    // normalized O through wave-private pw slab -> vector global store
    float inv[4];
#pragma unroll
    for (int r = 0; r < 4; r++) inv[r] = 1.0f / lrow[r];
#pragma unroll
    for (int nt = 0; nt < 4; nt++)
#pragma unroll
        for (int r = 0; r < 4; r++)
            pw[(G*4 + r)*LPAD + nt*16 + L] = f2bf(oacc[nt][r]*inv[r]);
    int orow = lane >> 2, oc = lane & 3;
    short8 o0 = *(short8*)(pw + orow*LPAD + oc*8);
    short8 o1 = *(short8*)(pw + orow*LPAD + 32 + oc*8);
    ushort_t* og = O + (size_t)(b*N_ + qBase + w*16 + orow)*D_ + h*HD_;
    *(short8*)(og + oc*8) = o0;
    *(short8*)(og + 32 + oc*8) = o1;
}

// ---------------------------------------------------------------------------
// Final projection v2: one wave per row (coalesced); pred[m,c] = X[m,:] @ pw[:,c]
__global__ __launch_bounds__(256) void proj_kernel(const float* __restrict__ X,
                                                   const float* __restrict__ pw,
                                                   float* __restrict__ pred) {
    int wid = threadIdx.x >> 6, lane = threadIdx.x & 63;
    int m = blockIdx.x*4 + wid;
    const float* xr = X + (size_t)m*D_;
    float a0 = 0.f, a1 = 0.f, a2 = 0.f;
#pragma unroll
    for (int i = 0; i < 6; i++) {
        int k = lane + i*64;
        float xv = xr[k];
        a0 += xv*pw[k*3+0]; a1 += xv*pw[k*3+1]; a2 += xv*pw[k*3+2];
    }
#pragma unroll
    for (int off = 32; off; off >>= 1) {
        a0 += __shfl_xor(a0, off, 64);
        a1 += __shfl_xor(a1, off, 64);
        a2 += __shfl_xor(a2, off, 64);
    }
    if (lane == 0) {
        pred[m*3+0] = a0; pred[m*3+1] = a1; pred[m*3+2] = a2;
    }
}

// ---------------------------------------------------------------------------
// FPS v6: VALU-throughput-optimized (R3 counters: active-CU VALUBusy ~82%).
//  (a) centers buffered in LDS, flushed after the loop -> no global store /
//      vmcnt drain inside the serial loop.
//  (b) packed-f32 distance math (v_pk_add/mul via inline asm, RN, unfused,
//      order (xx+yy)+zz preserved) -> 2 points per instruction.
//  (c) 1024 threads x 8 pts (4 waves/SIMD) for latency hiding.
// Reduction: DPP 16-lane argmax + 64 row slots -> 2-slot read + max ->
// DPP + swizzle16 merge. Tie-break exact: u64 (dist_bits<<32)|~p, max.
template<int CTRL>
__device__ __forceinline__ u64_t dpp_max64(u64_t x) {
    unsigned lo = (unsigned)x;
    unsigned hi = (unsigned)(x >> 32);
    lo = (unsigned)__builtin_amdgcn_update_dpp((int)lo, (int)lo, CTRL, 0xF, 0xF, false);
    hi = (unsigned)__builtin_amdgcn_update_dpp((int)hi, (int)hi, CTRL, 0xF, 0xF, false);
    u64_t o = ((u64_t)hi << 32) | lo;
    return (o > x) ? o : x;
}
__device__ __forceinline__ u64_t swz16_max64(u64_t x) {
    unsigned lo = (unsigned)x;
    unsigned hi = (unsigned)(x >> 32);
    lo = (unsigned)__builtin_amdgcn_ds_swizzle((int)lo, 0x401F);   // lane ^= 16 (within 32)
    hi = (unsigned)__builtin_amdgcn_ds_swizzle((int)hi, 0x401F);
    u64_t o = ((u64_t)hi << 32) | lo;
    return (o > x) ? o : x;
}
__device__ __forceinline__ floatx2 pk_sub(floatx2 a, floatx2 b) {
    floatx2 r;
    asm("v_pk_add_f32 %0, %1, %2 neg_lo:[0,1] neg_hi:[0,1]" : "=v"(r) : "v"(a), "v"(b));
    return r;
}
__device__ __forceinline__ floatx2 pk_mul(floatx2 a, floatx2 b) {
    floatx2 r;
    asm("v_pk_mul_f32 %0, %1, %2" : "=v"(r) : "v"(a), "v"(b));
    return r;
}
__device__ __forceinline__ floatx2 pk_add(floatx2 a, floatx2 b) {
    floatx2 r;
    asm("v_pk_add_f32 %0, %1, %2" : "=v"(r) : "v"(a), "v"(b));
    return r;
}

__global__ __launch_bounds__(1024) void fps_kernel(const float* __restrict__ pts,
                                                   float* __restrict__ centers) {
    __shared__ float Lx[P_], Ly[P_], Lz[P_];            // 96 KiB
    __shared__ float Cbuf[N_*3];                        // 12 KiB (centers staging)
    __shared__ u64_t slot[2][64];
    int b = blockIdx.x, t = threadIdx.x;
    const float* pb = pts + (size_t)b*P_*3;
    floatx2 px[4], py[4], pz[4];
    float dist[8];
#pragma unroll
    for (int j = 0; j < 8; j++) {
        int p = j*1024 + t;
        float x = pb[p*3+0], y = pb[p*3+1], z = pb[p*3+2];
        Lx[p] = x; Ly[p] = y; Lz[p] = z;
        px[j>>1][j&1] = x; py[j>>1][j&1] = y; pz[j>>1][j&1] = z;
        dist[j] = 1e10f;
    }
    int winner = 0;
    __syncthreads();
    for (int it = 0; it < N_; it++) {
        float lx = Lx[winner], ly = Ly[winner], lz = Lz[winner];
        if (t == 0) {
            Cbuf[it*3+0] = lx; Cbuf[it*3+1] = ly; Cbuf[it*3+2] = lz;
        }
        floatx2 lx2 = {lx, lx}, ly2 = {ly, ly}, lz2 = {lz, lz};
        // per-thread best: strict > with ascending j == smallest index on ties
        float bd = -1.0f; int bj = 0;
#pragma unroll
        for (int jj = 0; jj < 4; jj++) {
            floatx2 dx = pk_sub(px[jj], lx2);
            floatx2 dy = pk_sub(py[jj], ly2);
            floatx2 dz = pk_sub(pz[jj], lz2);
            // exact order: (dx*dx + dy*dy) + dz*dz, all RN, no contraction
            floatx2 d2 = pk_add(pk_add(pk_mul(dx,dx), pk_mul(dy,dy)), pk_mul(dz,dz));
            float d0 = fminf(dist[2*jj+0], d2[0]);
            dist[2*jj+0] = d0;
            bool g0 = d0 > bd; bd = g0 ? d0 : bd; bj = g0 ? 2*jj+0 : bj;
            float d1 = fminf(dist[2*jj+1], d2[1]);
            dist[2*jj+1] = d1;
            bool g1 = d1 > bd; bd = g1 ? d1 : bd; bj = g1 ? 2*jj+1 : bj;
        }
        // pack once: global idx p = bj*1024 + t (ascending in j), ~p -> first-wins
        u64_t best = ((u64_t)__float_as_uint(bd) << 32)
                   | (unsigned)(~(unsigned)((bj<<10) + t));
        // in-row (16-lane) argmax, pure VALU
        best = dpp_max64<0xB1>(best);    // quad_perm [1,0,3,2] : xor 1
        best = dpp_max64<0x4E>(best);    // quad_perm [2,3,0,1] : xor 2
        best = dpp_max64<0x124>(best);   // row_ror:4
        best = dpp_max64<0x128>(best);   // row_ror:8
        int par = it & 1;
        if ((t & 15) == 0) slot[par][t >> 4] = best;   // 64 row maxima
        __syncthreads();
        // cross-row merge: two slots per thread, butterfly to global max
        u64_t v0 = slot[par][t & 31];
        u64_t v1 = slot[par][(t & 31) + 32];
        u64_t v = (v1 > v0) ? v1 : v0;
        v = dpp_max64<0xB1>(v);
        v = dpp_max64<0x4E>(v);
        v = dpp_max64<0x124>(v);
        v = dpp_max64<0x128>(v);
        v = swz16_max64(v);              // xor 16 within each 32-lane half
        winner = (int)(~(unsigned)(v & 0xFFFFFFFFull));
    }
    __syncthreads();
    // coalesced centers flush (3072 floats, 3 per thread)
    float* cb = centers + (size_t)b*N_*3;
#pragma unroll
    for (int i = 0; i < 3; i++) cb[t + i*1024] = Cbuf[t + i*1024];
}

// ---------------------------------------------------------------------------
__global__ __launch_bounds__(256) void nnmin_kernel(const float* __restrict__ Asrc,
                                                    const float* __restrict__ Bsrc,
                                                    float* __restrict__ outmin) {
    int b = blockIdx.y;
    int i = blockIdx.x*256 + threadIdx.x;
    __shared__ float tile[256][3];
    const float* ar = Asrc + ((size_t)b*N_ + i)*3;
    float ax = ar[0], ay = ar[1], az = ar[2];
    float best = 3.0e38f;
    for (int j0 = 0; j0 < N_; j0 += 256) {
        __syncthreads();
        const float* br = Bsrc + ((size_t)b*N_ + j0 + threadIdx.x)*3;
        tile[threadIdx.x][0] = br[0]; tile[threadIdx.x][1] = br[1]; tile[threadIdx.x][2] = br[2];
        __syncthreads();
        for (int j = 0; j < 256; j++) {
            float dx = ax - tile[j][0], dy = ay - tile[j][1], dz = az - tile[j][2];
            float d = dx*dx + dy*dy + dz*dz;
            best = fminf(best, d);
        }
    }
    outmin[(size_t)b*N_ + i] = sqrtf(best);
}

__global__ __launch_bounds__(256) void knn_kernel(const float* __restrict__ Pp,
                                                  float* __restrict__ mean_d) {
    int b = blockIdx.y;
    int i = blockIdx.x*256 + threadIdx.x;
    __shared__ float tile[256][3];
    const float* ar = Pp + ((size_t)b*N_ + i)*3;
    float ax = ar[0], ay = ar[1], az = ar[2];
    float s[6];
#pragma unroll
    for (int q = 0; q < 6; q++) s[q] = 3.0e38f;
    for (int j0 = 0; j0 < N_; j0 += 256) {
        __syncthreads();
        const float* br = Pp + ((size_t)b*N_ + j0 + threadIdx.x)*3;
        tile[threadIdx.x][0] = br[0]; tile[threadIdx.x][1] = br[1]; tile[threadIdx.x][2] = br[2];
        __syncthreads();
        for (int j = 0; j < 256; j++) {
            float dx = ax - tile[j][0], dy = ay - tile[j][1], dz = az - tile[j][2];
            float d = dx*dx + dy*dy + dz*dz;
            if (d < s[5]) {
                s[5] = d;
#pragma unroll
                for (int q = 5; q > 0; q--)
                    if (s[q] < s[q-1]) { float tmp = s[q]; s[q] = s[q-1]; s[q-1] = tmp; }
            }
        }
    }
    float msum = sqrtf(s[1]) + sqrtf(s[2]) + sqrtf(s[3]) + sqrtf(s[4]) + sqrtf(s[5]);
    mean_d[(size_t)b*N_ + i] = msum * 0.2f;
}

__global__ __launch_bounds__(256) void kl_kernel(const float* __restrict__ md,
                                                 float* __restrict__ klb) {
    int b = blockIdx.x, t = threadIdx.x;
    const float* row = md + (size_t)b*N_;
    float v[4];
#pragma unroll
    for (int i = 0; i < 4; i++) v[i] = row[t + i*256];
    float mx = fmaxf(fmaxf(v[0], v[1]), fmaxf(v[2], v[3]));
#pragma unroll
    for (int off = 32; off; off >>= 1) mx = fmaxf(mx, __shfl_xor(mx, off, 64));
    __shared__ float redm[4], rse[4], rsx[4];
    int wid = t >> 6, lane = t & 63;
    if (lane == 0) redm[wid] = mx;
    __syncthreads();
    mx = fmaxf(fmaxf(redm[0], redm[1]), fmaxf(redm[2], redm[3]));
    float se = 0.f, sx = 0.f;
#pragma unroll
    for (int i = 0; i < 4; i++) { se += expf(v[i]-mx); sx += v[i]; }
#pragma unroll
    for (int off = 32; off; off >>= 1) { se += __shfl_xor(se, off, 64); sx += __shfl_xor(sx, off, 64); }
    if (lane == 0) { rse[wid] = se; rsx[wid] = sx; }
    __syncthreads();
    if (t == 0) {
        float SE = rse[0]+rse[1]+rse[2]+rse[3];
        float SX = rsx[0]+rsx[1]+rsx[2]+rsx[3];
        klb[b] = mx + logf(SE) - SX*(1.0f/(float)N_) - logf((float)N_);
    }
}

__global__ __launch_bounds__(256) void final_kernel(const float* __restrict__ rma,
                                                    const float* __restrict__ rmb,
                                                    const float* __restrict__ klb,
                                                    float* __restrict__ out) {
    int t = threadIdx.x;
    float s = 0.f;
    for (int i = t; i < B_*N_; i += 256) s += rma[i] + rmb[i];
#pragma unroll
    for (int off = 32; off; off >>= 1) s += __shfl_xor(s, off, 64);
    __shared__ float red[4];
    int wid = t >> 6, lane = t & 63;
    if (lane == 0) red[wid] = s;
    __syncthreads();
    if (t == 0) {
        float S = red[0]+red[1]+red[2]+red[3];
        out[0] = 0.5f*S/(float)(B_*N_);
        out[1] = 0.f;
        float K = 0.f;
        for (int b = 0; b < B_; b++) K += klb[b];
        out[1] = K/(float)B_;
    }
}

// ---------------------------------------------------------------------------
extern "C" void kernel_launch(void* const* d_in, const int* in_sizes, int n_in,
                              void* d_out, int out_size, void* d_ws, size_t ws_size,
                              hipStream_t stream) {
    (void)in_sizes; (void)n_in; (void)out_size; (void)ws_size;
    const float* pts     = (const float*)d_in[0];
    const float* grid    = (const float*)d_in[1];
    const float* embed_w = (const float*)d_in[2];
    const float* proj_w  = (const float*)d_in[3];
    const float* ln1_w   = (const float*)d_in[4];
    const float* ln1_b   = (const float*)d_in[5];
    const float* qkv_w   = (const float*)d_in[6];
    const float* qkv_b   = (const float*)d_in[7];
    const float* attn_w  = (const float*)d_in[8];
    const float* attn_b  = (const float*)d_in[9];
    const float* ln2_w   = (const float*)d_in[10];
    const float* ln2_b   = (const float*)d_in[11];
    const float* mlp_w1  = (const float*)d_in[12];
    const float* mlp_b1  = (const float*)d_in[13];
    const float* mlp_w2  = (const float*)d_in[14];
    const float* mlp_b2  = (const float*)d_in[15];
    float* out = (float*)d_out;

    // workspace layout (~144 MB)
    float*    X     = (float*)d_ws;                         // M*D f32
    ushort_t* Hb16  = (ushort_t*)(X + (size_t)M_*D_);       // M*D bf16
    ushort_t* BIG16 = Hb16 + (size_t)M_*D_;                 // M*1536 bf16 (QKV / MLP hidden)
    ushort_t* VT    = BIG16 + (size_t)M_*DH_;               // B*H*64*N bf16 (V transposed)
    ushort_t* WQ    = VT  + (size_t)B_*H_*HD_*N_;           // L*1152*384
    ushort_t* WA    = WQ  + (size_t)L_*DQKV_*D_;            // L*384*384
    ushort_t* WM1   = WA  + (size_t)L_*D_*D_;               // L*1536*384
    ushort_t* WM2   = WM1 + (size_t)L_*DH_*D_;              // L*384*1536
    float*    PRED  = (float*)(WM2 + (size_t)L_*D_*DH_);    // M*3
    float*    CENT  = PRED + (size_t)M_*3;                  // B*N*3
    float*    RMA   = CENT + (size_t)B_*N_*3;               // B*N
    float*    RMB   = RMA  + (size_t)B_*N_;                 // B*N
    float*    MEAND = RMB  + (size_t)B_*N_;                 // B*N
    float*    KLB   = MEAND + (size_t)B_*N_;                // B

    // one-time weight transpose-casts (f32 [K,N] -> bf16 [N,K])
    transcast_kernel<<<dim3(DQKV_/32, D_/32,  L_), 256, 0, stream>>>(qkv_w,  WQ,  D_,  DQKV_);
    transcast_kernel<<<dim3(D_/32,    D_/32,  L_), 256, 0, stream>>>(attn_w, WA,  D_,  D_);
    transcast_kernel<<<dim3(DH_/32,   D_/32,  L_), 256, 0, stream>>>(mlp_w1, WM1, D_,  DH_);
    transcast_kernel<<<dim3(D_/32,    DH_/32, L_), 256, 0, stream>>>(mlp_w2, WM2, DH_, D_);

    // FPS (independent of transformer)
    fps_kernel<<<B_, 1024, 0, stream>>>(pts, CENT);

    embed_kernel<<<M_, D_, 0, stream>>>(grid, embed_w, X);

    for (int l = 0; l < L_; l++) {
        ln_kernel<<<M_/4, 256, 0, stream>>>(X, ln1_w + l*D_, ln1_b + l*D_, Hb16);
        mfma_gemm<3><<<dim3(DQKV_/128, M_/128), 256, 0, stream>>>(
            Hb16, WQ + (size_t)l*DQKV_*D_, qkv_b + l*DQKV_, BIG16, VT, D_, DQKV_);
        fattn_kernel<<<dim3(N_/64, H_, B_), 256, 0, stream>>>(BIG16, VT, Hb16);
        mfma_gemm<1><<<dim3(D_/128, M_/128), 256, 0, stream>>>(
            Hb16, WA + (size_t)l*D_*D_, attn_b + l*D_, X, nullptr, D_, D_);
        ln_kernel<<<M_/4, 256, 0, stream>>>(X, ln2_w + l*D_, ln2_b + l*D_, Hb16);
        mfma_gemm<2><<<dim3(DH_/128, M_/128), 256, 0, stream>>>(
            Hb16, WM1 + (size_t)l*DH_*D_, mlp_b1 + l*DH_, BIG16, nullptr, D_, DH_);
        mfma_gemm<1><<<dim3(D_/128, M_/128), 256, 0, stream>>>(
            BIG16, WM2 + (size_t)l*D_*DH_, mlp_b2 + l*D_, X, nullptr, DH_, D_);
    }

    proj_kernel<<<M_/4, 256, 0, stream>>>(X, proj_w, PRED);

    nnmin_kernel<<<dim3(N_/256, B_), 256, 0, stream>>>(PRED, CENT, RMA);
    nnmin_kernel<<<dim3(N_/256, B_), 256, 0, stream>>>(CENT, PRED, RMB);
    knn_kernel<<<dim3(N_/256, B_), 256, 0, stream>>>(PRED, MEAND);
    kl_kernel<<<B_, 256, 0, stream>>>(MEAND, KLB);
    final_kernel<<<1, 256, 0, stream>>>(RMA, RMB, KLB, out);
}

// Round 10
// 4323.801 us; speedup vs baseline: 1.0691x; 1.0691x over previous
//
#include <hip/hip_runtime.h>
#include <math.h>

// Problem constants (GridSmoother)
#define B_   16
#define P_   8192
#define N_   1024
#define D_   384
#define L_   12
#define H_   6
#define HD_  64
#define M_   (B_*N_)     // 16384 rows
#define DQKV_ (3*D_)     // 1152
#define DH_   (4*D_)     // 1536

typedef unsigned short ushort_t;
typedef unsigned long long u64_t;
typedef __attribute__((ext_vector_type(8))) short short8;
typedef __attribute__((ext_vector_type(4))) float floatx4;
typedef __attribute__((ext_vector_type(2))) float floatx2;

// bf16 helpers (RNE), raw-bits representation
__device__ __forceinline__ ushort_t f2bf(float f) {
    unsigned u = __float_as_uint(f);
    unsigned rounding = 0x7fffu + ((u >> 16) & 1u);
    return (ushort_t)((u + rounding) >> 16);
}
__device__ __forceinline__ float bf2f(ushort_t u) {
    return __uint_as_float(((unsigned)u) << 16);
}

// ---------------------------------------------------------------------------
// Embed: X[m,d] = sum_k grid[m,k] * ew[k,d]   (K=3)
__global__ __launch_bounds__(D_) void embed_kernel(const float* __restrict__ g,
                                                   const float* __restrict__ ew,
                                                   float* __restrict__ X) {
    int m = blockIdx.x;
    int d = threadIdx.x;
    float g0 = g[m*3+0], g1 = g[m*3+1], g2 = g[m*3+2];
    X[(size_t)m*D_ + d] = g0*ew[0*D_+d] + g1*ew[1*D_+d] + g2*ew[2*D_+d];
}

// ---------------------------------------------------------------------------
// Weight transpose-cast: W [L][K][N] f32 -> Wt [L][N][K] bf16 bits
__global__ __launch_bounds__(256) void transcast_kernel(const float* __restrict__ W,
                                                        ushort_t* __restrict__ Wt,
                                                        int K, int Nc) {
    __shared__ float t[32][33];
    const float* Wl = W + (size_t)blockIdx.z*K*Nc;
    ushort_t* Wtl = Wt + (size_t)blockIdx.z*K*Nc;
    int n0 = blockIdx.x*32, k0 = blockIdx.y*32;
    int tx = threadIdx.x & 31, ty = threadIdx.x >> 5;   // 32 x 8
#pragma unroll
    for (int j = 0; j < 32; j += 8)
        t[ty+j][tx] = Wl[(size_t)(k0+ty+j)*Nc + n0+tx];
    __syncthreads();
#pragma unroll
    for (int j = 0; j < 32; j += 8)
        Wtl[(size_t)(n0+ty+j)*K + k0+tx] = f2bf(t[tx][ty+j]);
}

// ---------------------------------------------------------------------------
// LayerNorm: one wave per row of 384; reads f32 X, writes bf16 bits.
__global__ __launch_bounds__(256) void ln_kernel(const float* __restrict__ Xin,
                                                 const float* __restrict__ w,
                                                 const float* __restrict__ bvec,
                                                 ushort_t* __restrict__ out) {
    int wid = threadIdx.x >> 6, lane = threadIdx.x & 63;
    int row = blockIdx.x*4 + wid;
    const float* xr = Xin + (size_t)row*D_;
    float v[6];
#pragma unroll
    for (int i = 0; i < 6; i++) v[i] = xr[lane + i*64];
    float s = 0.f;
#pragma unroll
    for (int i = 0; i < 6; i++) s += v[i];
#pragma unroll
    for (int off = 32; off; off >>= 1) s += __shfl_xor(s, off, 64);
    float mean = s * (1.0f/(float)D_);
    float vs = 0.f;
#pragma unroll
    for (int i = 0; i < 6; i++) { float d = v[i]-mean; vs += d*d; }
#pragma unroll
    for (int off = 32; off; off >>= 1) vs += __shfl_xor(vs, off, 64);
    float var = vs * (1.0f/(float)D_);
    float rstd = 1.0f / sqrtf(var + 1e-5f);
    ushort_t* orow = out + (size_t)row*D_;
#pragma unroll
    for (int i = 0; i < 6; i++) {
        int e = lane + i*64;
        orow[e] = f2bf((v[i]-mean)*rstd*w[e] + bvec[e]);
    }
}

// ---------------------------------------------------------------------------
__device__ __forceinline__ float gelu_f(float x) {
    const float c = 0.7978845608028654f;   // sqrt(2/pi)
    float x3 = x*x*x;
    return 0.5f*x*(1.0f + tanhf(c*(x + 0.044715f*x3)));
}

// ---------------------------------------------------------------------------
// MFMA bf16 GEMM v2 (R5 configuration — LDS stride 32, 16B-aligned b128):
// register-prefetch staging, vectorized epilogues.
// EPI: 0 = bias -> bf16 out; 1 = bias + residual add into f32 C;
//      2 = gelu(bias+acc) -> bf16 out;
//      3 = QKV split: cols<768 packed bf16, cols>=768 scatter to VT.
template<int EPI>
__global__ __launch_bounds__(256) void mfma_gemm(const ushort_t* __restrict__ A,
                                                 const ushort_t* __restrict__ Wt,
                                                 const float* __restrict__ bias,
                                                 void* __restrict__ Cout,
                                                 ushort_t* __restrict__ VT,
                                                 int K, int Nc) {
    __shared__ __attribute__((aligned(16))) ushort_t smem[2*128*32];   // 16 KB
    ushort_t* smA = smem;
    ushort_t* smB = smem + 128*32;
    int tid = threadIdx.x;
    int lane = tid & 63, w = tid >> 6;
    int wm = w >> 1, wn = w & 1;
    int L = lane & 15, G = lane >> 4;
    int rowBase = blockIdx.y * 128, colBase = blockIdx.x * 128;

    floatx4 acc[4][4];
#pragma unroll
    for (int i = 0; i < 4; i++)
#pragma unroll
        for (int j = 0; j < 4; j++) acc[i][j] = (floatx4){0.f,0.f,0.f,0.f};

    // staging map: 256 threads x 2 chunks per buffer; chunk = 16B = 8 bf16
    int sr = tid >> 2;          // row 0..63 (and +64)
    int kc = tid & 3;           // k-chunk 0..3
    const ushort_t* Ag = A  + (size_t)(rowBase + sr)*K + kc*8;
    const ushort_t* Bg = Wt + (size_t)(colBase + sr)*K + kc*8;
    size_t step64 = (size_t)64*K;

    short8 ra0, ra1, rb0, rb1;
    ra0 = *(const short8*)(Ag);
    ra1 = *(const short8*)(Ag + step64);
    rb0 = *(const short8*)(Bg);
    rb1 = *(const short8*)(Bg + step64);

    for (int k0 = 0; k0 < K; k0 += 32) {
        __syncthreads();
        *(short8*)(smA + sr*32 + kc*8)        = ra0;
        *(short8*)(smA + (64+sr)*32 + kc*8)   = ra1;
        *(short8*)(smB + sr*32 + kc*8)        = rb0;
        *(short8*)(smB + (64+sr)*32 + kc*8)   = rb1;
        __syncthreads();
        if (k0 + 32 < K) {      // prefetch next k-slab; loads stay in flight
            ra0 = *(const short8*)(Ag + k0 + 32);
            ra1 = *(const short8*)(Ag + step64 + k0 + 32);
            rb0 = *(const short8*)(Bg + k0 + 32);
            rb1 = *(const short8*)(Bg + step64 + k0 + 32);
        }
        short8 af[4], bfr[4];
#pragma unroll
        for (int t = 0; t < 4; t++) {
            af[t]  = *(const short8*)(smA + (wm*64 + t*16 + L)*32 + G*8);
            bfr[t] = *(const short8*)(smB + (wn*64 + t*16 + L)*32 + G*8);
        }
#pragma unroll
        for (int mt = 0; mt < 4; mt++)
#pragma unroll
            for (int nt = 0; nt < 4; nt++)
                acc[mt][nt] = __builtin_amdgcn_mfma_f32_16x16x32_bf16(
                    af[mt], bfr[nt], acc[mt][nt], 0, 0, 0);
        __syncthreads();
    }

    __syncthreads();   // smem reuse for epilogue

    if (EPI == 3 && colBase >= 2*D_) {
        // pure-V column block: scalar scatter into VT[b,h,d,n]
        int cBase = colBase + wn*64 + L;
        int rBase = rowBase + wm*64 + G*4;
#pragma unroll
        for (int nt = 0; nt < 4; nt++) {
            int col = cBase + nt*16;
            float bv = bias[col];
            int hh = (col - 2*D_) >> 6, d = (col - 2*D_) & 63;
#pragma unroll
            for (int mt = 0; mt < 4; mt++) {
#pragma unroll
                for (int r = 0; r < 4; r++) {
                    int row = rBase + mt*16 + r;
                    int b = row >> 10, n = row & 1023;
                    VT[(((size_t)b*H_ + hh)*64 + d)*N_ + n] = f2bf(acc[mt][nt][r] + bv);
                }
            }
        }
    } else if (EPI == 1) {
        // f32 residual add, vectorized via per-wave LDS slab (16x64 f32)
        float* fs = (float*)smem + w*1024;
        int orow = lane >> 2, c4 = lane & 3;
#pragma unroll
        for (int mt = 0; mt < 4; mt++) {
#pragma unroll
            for (int nt = 0; nt < 4; nt++) {
                float bv = bias[colBase + wn*64 + nt*16 + L];
#pragma unroll
                for (int r = 0; r < 4; r++)
                    fs[(G*4+r)*64 + nt*16 + L] = acc[mt][nt][r] + bv;
            }
            float* og = (float*)Cout + (size_t)(rowBase + wm*64 + mt*16 + orow)*Nc
                        + colBase + wn*64;
#pragma unroll
            for (int kk = 0; kk < 4; kk++) {
                float4 sv = *(float4*)(fs + orow*64 + kk*16 + c4*4);
                float4 gv = *(float4*)(og + kk*16 + c4*4);
                gv.x += sv.x; gv.y += sv.y; gv.z += sv.z; gv.w += sv.w;
                *(float4*)(og + kk*16 + c4*4) = gv;
            }
        }
    } else {
        // bf16 out (EPI 0/2/3-QK), vectorized via per-wave LDS slab (stride 72)
        ushort_t* us = smem + w*1152;
        int orow = lane >> 2, oc = lane & 3;
#pragma unroll
        for (int mt = 0; mt < 4; mt++) {
#pragma unroll
            for (int nt = 0; nt < 4; nt++) {
                float bv = bias[colBase + wn*64 + nt*16 + L];
#pragma unroll
                for (int r = 0; r < 4; r++) {
                    float v = acc[mt][nt][r] + bv;
                    if (EPI == 2) v = gelu_f(v);
                    us[(G*4+r)*72 + nt*16 + L] = f2bf(v);
                }
            }
            short8 o0 = *(short8*)(us + orow*72 + oc*8);
            short8 o1 = *(short8*)(us + orow*72 + 32 + oc*8);
            ushort_t* og = (ushort_t*)Cout + (size_t)(rowBase + wm*64 + mt*16 + orow)*Nc
                           + colBase + wn*64;
            *(short8*)(og + oc*8) = o0;
            *(short8*)(og + 32 + oc*8) = o1;
        }
    }
}

// ---------------------------------------------------------------------------
// Flash attention v2 (R5 configuration): 64-key tiles, register-prefetch
// staging, 2 barriers/tile, wave-private P round-trip, vectorized O store.
// LPAD 72 elements = 144 B (16B-aligned for b128).
#define LPAD 72
__global__ __launch_bounds__(256) void fattn_kernel(const ushort_t* __restrict__ QKV,
                                                    const ushort_t* __restrict__ VT,
                                                    ushort_t* __restrict__ O) {
    __shared__ __attribute__((aligned(16))) ushort_t Ks[64*LPAD];
    __shared__ __attribute__((aligned(16))) ushort_t Vs[64*LPAD];
    __shared__ __attribute__((aligned(16))) ushort_t Pw[4*16*LPAD];
    int b = blockIdx.z, h = blockIdx.y;
    int qBase = blockIdx.x * 64;
    int tid = threadIdx.x;
    int lane = tid & 63, w = tid >> 6;
    int L = lane & 15, G = lane >> 4;

    short8 qf[2];
    {
        const ushort_t* qp = QKV + ((size_t)(b*N_ + qBase + w*16 + L))*DQKV_ + h*HD_ + G*8;
        qf[0] = *(const short8*)(qp);
        qf[1] = *(const short8*)(qp + 32);
    }

    floatx4 oacc[4];
#pragma unroll
    for (int nt = 0; nt < 4; nt++) oacc[nt] = (floatx4){0.f,0.f,0.f,0.f};
    float mrow[4], lrow[4];
#pragma unroll
    for (int r = 0; r < 4; r++) { mrow[r] = -3.0e38f; lrow[r] = 0.f; }

    ushort_t* pw = Pw + w*16*LPAD;
    const ushort_t* Kbase = QKV + (size_t)b*N_*DQKV_ + D_ + h*HD_;
    const ushort_t* Vbase = VT + ((size_t)b*H_ + h)*64*N_;

    // staging map: 512 chunks (16B) per buffer; thread covers chunk tid and tid+256
    int srow = tid >> 3;         // 0..31 (and +32)
    int dc   = tid & 7;
    const ushort_t* Kg0 = Kbase + (size_t)srow*DQKV_ + dc*8;
    const ushort_t* Kg1 = Kbase + (size_t)(srow+32)*DQKV_ + dc*8;
    const ushort_t* Vg0 = Vbase + (size_t)srow*N_ + dc*8;       // srow = d-row for V
    const ushort_t* Vg1 = Vbase + (size_t)(srow+32)*N_ + dc*8;

    short8 rk0, rk1, rv0, rv1;
    rk0 = *(const short8*)(Kg0);
    rk1 = *(const short8*)(Kg1);
    rv0 = *(const short8*)(Vg0);
    rv1 = *(const short8*)(Vg1);

    for (int kt = 0; kt < N_/64; kt++) {
        __syncthreads();   // prior tile's PV reads of Ks/Vs complete
        *(short8*)(Ks + srow*LPAD + dc*8)       = rk0;
        *(short8*)(Ks + (srow+32)*LPAD + dc*8)  = rk1;
        *(short8*)(Vs + srow*LPAD + dc*8)       = rv0;
        *(short8*)(Vs + (srow+32)*LPAD + dc*8)  = rv1;
        __syncthreads();
        if (kt + 1 < N_/64) {   // prefetch next tile (in flight across compute)
            rk0 = *(const short8*)(Kg0 + (size_t)(kt+1)*64*DQKV_);
            rk1 = *(const short8*)(Kg1 + (size_t)(kt+1)*64*DQKV_);
            rv0 = *(const short8*)(Vg0 + (kt+1)*64);
            rv1 = *(const short8*)(Vg1 + (kt+1)*64);
        }

        // S = Q K^T  (16 q-rows x 64 keys per wave)
        floatx4 sc[4];
#pragma unroll
        for (int ct = 0; ct < 4; ct++) sc[ct] = (floatx4){0.f,0.f,0.f,0.f};
#pragma unroll
        for (int ks = 0; ks < 2; ks++)
#pragma unroll
            for (int ct = 0; ct < 4; ct++) {
                short8 bf = *(const short8*)(Ks + (ct*16 + L)*LPAD + ks*32 + G*8);
                sc[ct] = __builtin_amdgcn_mfma_f32_16x16x32_bf16(qf[ks], bf, sc[ct], 0, 0, 0);
            }

        // online softmax over this 64-key tile
        float rmax[4], rsum[4];
#pragma unroll
        for (int r = 0; r < 4; r++) {
#pragma unroll
            for (int ct = 0; ct < 4; ct++) sc[ct][r] *= 0.125f;
            rmax[r] = fmaxf(fmaxf(sc[0][r], sc[1][r]), fmaxf(sc[2][r], sc[3][r]));
        }
#pragma unroll
        for (int off = 1; off < 16; off <<= 1)
#pragma unroll
            for (int r = 0; r < 4; r++) rmax[r] = fmaxf(rmax[r], __shfl_xor(rmax[r], off, 64));
        float corr[4];
#pragma unroll
        for (int r = 0; r < 4; r++) {
            float mn = fmaxf(mrow[r], rmax[r]);
            corr[r] = __expf(mrow[r] - mn);
            mrow[r] = mn;
            rsum[r] = 0.f;
#pragma unroll
            for (int ct = 0; ct < 4; ct++) {
                float p = __expf(sc[ct][r] - mn);
                sc[ct][r] = p;
                rsum[r] += p;
            }
        }
#pragma unroll
        for (int off = 1; off < 16; off <<= 1)
#pragma unroll
            for (int r = 0; r < 4; r++) rsum[r] += __shfl_xor(rsum[r], off, 64);
#pragma unroll
        for (int r = 0; r < 4; r++) lrow[r] = lrow[r]*corr[r] + rsum[r];

        // P (C-layout) -> wave-private LDS -> A-layout (in-wave ordering, no barrier)
#pragma unroll
        for (int ct = 0; ct < 4; ct++)
#pragma unroll
            for (int r = 0; r < 4; r++)
                pw[(G*4 + r)*LPAD + ct*16 + L] = f2bf(sc[ct][r]);
#pragma unroll
        for (int nt = 0; nt < 4; nt++)
#pragma unroll
            for (int r = 0; r < 4; r++) oacc[nt][r] *= corr[r];

        // O += P V
#pragma unroll
        for (int ks = 0; ks < 2; ks++) {
            short8 pf = *(const short8*)(pw + L*LPAD + ks*32 + G*8);
#pragma unroll
            for (int nt = 0; nt < 4; nt++) {
                short8 vf = *(const short8*)(Vs + (nt*16 + L)*LPAD + ks*32 + G*8);
                oacc[nt] = __builtin_amdgcn_mfma_f32_16x16x32_bf16(pf, vf, oacc[nt], 0, 0, 0);
            }
        }
    }

    // normalized O through wave-private pw slab -> vector global store
    float inv[4];
#pragma unroll
    for (int r = 0; r < 4; r++) inv[r] = 1.0f / lrow[r];
#pragma unroll
    for (int nt = 0; nt < 4; nt++)
#pragma unroll
        for (int r = 0; r < 4; r++)
            pw[(G*4 + r)*LPAD + nt*16 + L] = f2bf(oacc[nt][r]*inv[r]);
    int orow = lane >> 2, oc = lane & 3;
    short8 o0 = *(short8*)(pw + orow*LPAD + oc*8);
    short8 o1 = *(short8*)(pw + orow*LPAD + 32 + oc*8);
    ushort_t* og = O + (size_t)(b*N_ + qBase + w*16 + orow)*D_ + h*HD_;
    *(short8*)(og + oc*8) = o0;
    *(short8*)(og + 32 + oc*8) = o1;
}

// ---------------------------------------------------------------------------
// Final projection v2: one wave per row (coalesced); pred[m,c] = X[m,:] @ pw[:,c]
__global__ __launch_bounds__(256) void proj_kernel(const float* __restrict__ X,
                                                   const float* __restrict__ pw,
                                                   float* __restrict__ pred) {
    int wid = threadIdx.x >> 6, lane = threadIdx.x & 63;
    int m = blockIdx.x*4 + wid;
    const float* xr = X + (size_t)m*D_;
    float a0 = 0.f, a1 = 0.f, a2 = 0.f;
#pragma unroll
    for (int i = 0; i < 6; i++) {
        int k = lane + i*64;
        float xv = xr[k];
        a0 += xv*pw[k*3+0]; a1 += xv*pw[k*3+1]; a2 += xv*pw[k*3+2];
    }
#pragma unroll
    for (int off = 32; off; off >>= 1) {
        a0 += __shfl_xor(a0, off, 64);
        a1 += __shfl_xor(a1, off, 64);
        a2 += __shfl_xor(a2, off, 64);
    }
    if (lane == 0) {
        pred[m*3+0] = a0; pred[m*3+1] = a1; pred[m*3+2] = a2;
    }
}

// ---------------------------------------------------------------------------
// FPS v7: barrier/latency-bound model (R8 post-mortem: v6's 16 waves REGRESSED
// 918->1160; loop is lockstep-serial, extra waves only add barrier overhead).
// Minimum wave count that uses all 4 SIMDs: 256 threads (4 waves), 32 pts/thr.
// Keeps v6's HW-verified pieces: packed v_pk math (bit-exact) + LDS centers
// staging. Merge simplified to 16 slots: one slot read + 4 DPP levels.
// Tie-break exact: u64 (dist_bits<<32)|~(bj*256+t), max-reduce.
template<int CTRL>
__device__ __forceinline__ u64_t dpp_max64(u64_t x) {
    unsigned lo = (unsigned)x;
    unsigned hi = (unsigned)(x >> 32);
    lo = (unsigned)__builtin_amdgcn_update_dpp((int)lo, (int)lo, CTRL, 0xF, 0xF, false);
    hi = (unsigned)__builtin_amdgcn_update_dpp((int)hi, (int)hi, CTRL, 0xF, 0xF, false);
    u64_t o = ((u64_t)hi << 32) | lo;
    return (o > x) ? o : x;
}
__device__ __forceinline__ floatx2 pk_sub(floatx2 a, floatx2 b) {
    floatx2 r;
    asm("v_pk_add_f32 %0, %1, %2 neg_lo:[0,1] neg_hi:[0,1]" : "=v"(r) : "v"(a), "v"(b));
    return r;
}
__device__ __forceinline__ floatx2 pk_mul(floatx2 a, floatx2 b) {
    floatx2 r;
    asm("v_pk_mul_f32 %0, %1, %2" : "=v"(r) : "v"(a), "v"(b));
    return r;
}
__device__ __forceinline__ floatx2 pk_add(floatx2 a, floatx2 b) {
    floatx2 r;
    asm("v_pk_add_f32 %0, %1, %2" : "=v"(r) : "v"(a), "v"(b));
    return r;
}

__global__ __launch_bounds__(256) void fps_kernel(const float* __restrict__ pts,
                                                  float* __restrict__ centers) {
    __shared__ float Lx[P_], Ly[P_], Lz[P_];            // 96 KiB
    __shared__ float Cbuf[N_*3];                        // 12 KiB (centers staging)
    __shared__ u64_t slot[2][16];
    int b = blockIdx.x, t = threadIdx.x;
    const float* pb = pts + (size_t)b*P_*3;
    floatx2 px[16], py[16], pz[16];
    float dist[32];
#pragma unroll
    for (int j = 0; j < 32; j++) {
        int p = j*256 + t;
        float x = pb[p*3+0], y = pb[p*3+1], z = pb[p*3+2];
        Lx[p] = x; Ly[p] = y; Lz[p] = z;
        px[j>>1][j&1] = x; py[j>>1][j&1] = y; pz[j>>1][j&1] = z;
        dist[j] = 1e10f;
    }
    int winner = 0;
    __syncthreads();
    for (int it = 0; it < N_; it++) {
        float lx = Lx[winner], ly = Ly[winner], lz = Lz[winner];
        if (t == 0) {
            Cbuf[it*3+0] = lx; Cbuf[it*3+1] = ly; Cbuf[it*3+2] = lz;
        }
        floatx2 lx2 = {lx, lx}, ly2 = {ly, ly}, lz2 = {lz, lz};
        // per-thread best: strict > with ascending j == smallest index on ties
        float bd = -1.0f; int bj = 0;
#pragma unroll
        for (int jj = 0; jj < 16; jj++) {
            floatx2 dx = pk_sub(px[jj], lx2);
            floatx2 dy = pk_sub(py[jj], ly2);
            floatx2 dz = pk_sub(pz[jj], lz2);
            // exact order: (dx*dx + dy*dy) + dz*dz, all RN, no contraction
            floatx2 d2 = pk_add(pk_add(pk_mul(dx,dx), pk_mul(dy,dy)), pk_mul(dz,dz));
            float d0 = fminf(dist[2*jj+0], d2[0]);
            dist[2*jj+0] = d0;
            bool g0 = d0 > bd; bd = g0 ? d0 : bd; bj = g0 ? 2*jj+0 : bj;
            float d1 = fminf(dist[2*jj+1], d2[1]);
            dist[2*jj+1] = d1;
            bool g1 = d1 > bd; bd = g1 ? d1 : bd; bj = g1 ? 2*jj+1 : bj;
        }
        // pack once: global idx p = bj*256 + t (ascending in j), ~p -> first-wins
        u64_t best = ((u64_t)__float_as_uint(bd) << 32)
                   | (unsigned)(~(unsigned)((bj<<8) + t));
        // in-row (16-lane) argmax, pure VALU
        best = dpp_max64<0xB1>(best);    // quad_perm [1,0,3,2] : xor 1
        best = dpp_max64<0x4E>(best);    // quad_perm [2,3,0,1] : xor 2
        best = dpp_max64<0x124>(best);   // row_ror:4
        best = dpp_max64<0x128>(best);   // row_ror:8
        int par = it & 1;
        if ((t & 15) == 0) slot[par][t >> 4] = best;   // 16 row maxima (4 waves x 4 rows)
        __syncthreads();
        // cross-row merge: one slot per lane, 4 DPP levels -> global max in all lanes
        u64_t v = slot[par][t & 15];
        v = dpp_max64<0xB1>(v);
        v = dpp_max64<0x4E>(v);
        v = dpp_max64<0x124>(v);
        v = dpp_max64<0x128>(v);
        winner = (int)(~(unsigned)(v & 0xFFFFFFFFull));
    }
    __syncthreads();
    // coalesced centers flush (3072 floats, 12 per thread)
    float* cb = centers + (size_t)b*N_*3;
#pragma unroll
    for (int i = 0; i < 12; i++) cb[t + i*256] = Cbuf[t + i*256];
}

// ---------------------------------------------------------------------------
__global__ __launch_bounds__(256) void nnmin_kernel(const float* __restrict__ Asrc,
                                                    const float* __restrict__ Bsrc,
                                                    float* __restrict__ outmin) {
    int b = blockIdx.y;
    int i = blockIdx.x*256 + threadIdx.x;
    __shared__ float tile[256][3];
    const float* ar = Asrc + ((size_t)b*N_ + i)*3;
    float ax = ar[0], ay = ar[1], az = ar[2];
    float best = 3.0e38f;
    for (int j0 = 0; j0 < N_; j0 += 256) {
        __syncthreads();
        const float* br = Bsrc + ((size_t)b*N_ + j0 + threadIdx.x)*3;
        tile[threadIdx.x][0] = br[0]; tile[threadIdx.x][1] = br[1]; tile[threadIdx.x][2] = br[2];
        __syncthreads();
        for (int j = 0; j < 256; j++) {
            float dx = ax - tile[j][0], dy = ay - tile[j][1], dz = az - tile[j][2];
            float d = dx*dx + dy*dy + dz*dz;
            best = fminf(best, d);
        }
    }
    outmin[(size_t)b*N_ + i] = sqrtf(best);
}

__global__ __launch_bounds__(256) void knn_kernel(const float* __restrict__ Pp,
                                                  float* __restrict__ mean_d) {
    int b = blockIdx.y;
    int i = blockIdx.x*256 + threadIdx.x;
    __shared__ float tile[256][3];
    const float* ar = Pp + ((size_t)b*N_ + i)*3;
    float ax = ar[0], ay = ar[1], az = ar[2];
    float s[6];
#pragma unroll
    for (int q = 0; q < 6; q++) s[q] = 3.0e38f;
    for (int j0 = 0; j0 < N_; j0 += 256) {
        __syncthreads();
        const float* br = Pp + ((size_t)b*N_ + j0 + threadIdx.x)*3;
        tile[threadIdx.x][0] = br[0]; tile[threadIdx.x][1] = br[1]; tile[threadIdx.x][2] = br[2];
        __syncthreads();
        for (int j = 0; j < 256; j++) {
            float dx = ax - tile[j][0], dy = ay - tile[j][1], dz = az - tile[j][2];
            float d = dx*dx + dy*dy + dz*dz;
            if (d < s[5]) {
                s[5] = d;
#pragma unroll
                for (int q = 5; q > 0; q--)
                    if (s[q] < s[q-1]) { float tmp = s[q]; s[q] = s[q-1]; s[q-1] = tmp; }
            }
        }
    }
    float msum = sqrtf(s[1]) + sqrtf(s[2]) + sqrtf(s[3]) + sqrtf(s[4]) + sqrtf(s[5]);
    mean_d[(size_t)b*N_ + i] = msum * 0.2f;
}

__global__ __launch_bounds__(256) void kl_kernel(const float* __restrict__ md,
                                                 float* __restrict__ klb) {
    int b = blockIdx.x, t = threadIdx.x;
    const float* row = md + (size_t)b*N_;
    float v[4];
#pragma unroll
    for (int i = 0; i < 4; i++) v[i] = row[t + i*256];
    float mx = fmaxf(fmaxf(v[0], v[1]), fmaxf(v[2], v[3]));
#pragma unroll
    for (int off = 32; off; off >>= 1) mx = fmaxf(mx, __shfl_xor(mx, off, 64));
    __shared__ float redm[4], rse[4], rsx[4];
    int wid = t >> 6, lane = t & 63;
    if (lane == 0) redm[wid] = mx;
    __syncthreads();
    mx = fmaxf(fmaxf(redm[0], redm[1]), fmaxf(redm[2], redm[3]));
    float se = 0.f, sx = 0.f;
#pragma unroll
    for (int i = 0; i < 4; i++) { se += expf(v[i]-mx); sx += v[i]; }
#pragma unroll
    for (int off = 32; off; off >>= 1) { se += __shfl_xor(se, off, 64); sx += __shfl_xor(sx, off, 64); }
    if (lane == 0) { rse[wid] = se; rsx[wid] = sx; }
    __syncthreads();
    if (t == 0) {
        float SE = rse[0]+rse[1]+rse[2]+rse[3];
        float SX = rsx[0]+rsx[1]+rsx[2]+rsx[3];
        klb[b] = mx + logf(SE) - SX*(1.0f/(float)N_) - logf((float)N_);
    }
}

__global__ __launch_bounds__(256) void final_kernel(const float* __restrict__ rma,
                                                    const float* __restrict__ rmb,
                                                    const float* __restrict__ klb,
                                                    float* __restrict__ out) {
    int t = threadIdx.x;
    float s = 0.f;
    for (int i = t; i < B_*N_; i += 256) s += rma[i] + rmb[i];
#pragma unroll
    for (int off = 32; off; off >>= 1) s += __shfl_xor(s, off, 64);
    __shared__ float red[4];
    int wid = t >> 6, lane = t & 63;
    if (lane == 0) red[wid] = s;
    __syncthreads();
    if (t == 0) {
        float S = red[0]+red[1]+red[2]+red[3];
        out[0] = 0.5f*S/(float)(B_*N_);
        out[1] = 0.f;
        float K = 0.f;
        for (int b = 0; b < B_; b++) K += klb[b];
        out[1] = K/(float)B_;
    }
}

// ---------------------------------------------------------------------------
extern "C" void kernel_launch(void* const* d_in, const int* in_sizes, int n_in,
                              void* d_out, int out_size, void* d_ws, size_t ws_size,
                              hipStream_t stream) {
    (void)in_sizes; (void)n_in; (void)out_size; (void)ws_size;
    const float* pts     = (const float*)d_in[0];
    const float* grid    = (const float*)d_in[1];
    const float* embed_w = (const float*)d_in[2];
    const float* proj_w  = (const float*)d_in[3];
    const float* ln1_w   = (const float*)d_in[4];
    const float* ln1_b   = (const float*)d_in[5];
    const float* qkv_w   = (const float*)d_in[6];
    const float* qkv_b   = (const float*)d_in[7];
    const float* attn_w  = (const float*)d_in[8];
    const float* attn_b  = (const float*)d_in[9];
    const float* ln2_w   = (const float*)d_in[10];
    const float* ln2_b   = (const float*)d_in[11];
    const float* mlp_w1  = (const float*)d_in[12];
    const float* mlp_b1  = (const float*)d_in[13];
    const float* mlp_w2  = (const float*)d_in[14];
    const float* mlp_b2  = (const float*)d_in[15];
    float* out = (float*)d_out;

    // workspace layout (~144 MB)
    float*    X     = (float*)d_ws;                         // M*D f32
    ushort_t* Hb16  = (ushort_t*)(X + (size_t)M_*D_);       // M*D bf16
    ushort_t* BIG16 = Hb16 + (size_t)M_*D_;                 // M*1536 bf16 (QKV / MLP hidden)
    ushort_t* VT    = BIG16 + (size_t)M_*DH_;               // B*H*64*N bf16 (V transposed)
    ushort_t* WQ    = VT  + (size_t)B_*H_*HD_*N_;           // L*1152*384
    ushort_t* WA    = WQ  + (size_t)L_*DQKV_*D_;            // L*384*384
    ushort_t* WM1   = WA  + (size_t)L_*D_*D_;               // L*1536*384
    ushort_t* WM2   = WM1 + (size_t)L_*DH_*D_;              // L*384*1536
    float*    PRED  = (float*)(WM2 + (size_t)L_*D_*DH_);    // M*3
    float*    CENT  = PRED + (size_t)M_*3;                  // B*N*3
    float*    RMA   = CENT + (size_t)B_*N_*3;               // B*N
    float*    RMB   = RMA  + (size_t)B_*N_;                 // B*N
    float*    MEAND = RMB  + (size_t)B_*N_;                 // B*N
    float*    KLB   = MEAND + (size_t)B_*N_;                // B

    // one-time weight transpose-casts (f32 [K,N] -> bf16 [N,K])
    transcast_kernel<<<dim3(DQKV_/32, D_/32,  L_), 256, 0, stream>>>(qkv_w,  WQ,  D_,  DQKV_);
    transcast_kernel<<<dim3(D_/32,    D_/32,  L_), 256, 0, stream>>>(attn_w, WA,  D_,  D_);
    transcast_kernel<<<dim3(DH_/32,   D_/32,  L_), 256, 0, stream>>>(mlp_w1, WM1, D_,  DH_);
    transcast_kernel<<<dim3(D_/32,    DH_/32, L_), 256, 0, stream>>>(mlp_w2, WM2, DH_, D_);

    // FPS (independent of transformer)
    fps_kernel<<<B_, 256, 0, stream>>>(pts, CENT);

    embed_kernel<<<M_, D_, 0, stream>>>(grid, embed_w, X);

    for (int l = 0; l < L_; l++) {
        ln_kernel<<<M_/4, 256, 0, stream>>>(X, ln1_w + l*D_, ln1_b + l*D_, Hb16);
        mfma_gemm<3><<<dim3(DQKV_/128, M_/128), 256, 0, stream>>>(
            Hb16, WQ + (size_t)l*DQKV_*D_, qkv_b + l*DQKV_, BIG16, VT, D_, DQKV_);
        fattn_kernel<<<dim3(N_/64, H_, B_), 256, 0, stream>>>(BIG16, VT, Hb16);
        mfma_gemm<1><<<dim3(D_/128, M_/128), 256, 0, stream>>>(
            Hb16, WA + (size_t)l*D_*D_, attn_b + l*D_, X, nullptr, D_, D_);
        ln_kernel<<<M_/4, 256, 0, stream>>>(X, ln2_w + l*D_, ln2_b + l*D_, Hb16);
        mfma_gemm<2><<<dim3(DH_/128, M_/128), 256, 0, stream>>>(
            Hb16, WM1 + (size_t)l*DH_*D_, mlp_b1 + l*DH_, BIG16, nullptr, D_, DH_);
        mfma_gemm<1><<<dim3(D_/128, M_/128), 256, 0, stream>>>(
            BIG16, WM2 + (size_t)l*D_*DH_, mlp_b2 + l*D_, X, nullptr, DH_, D_);
    }

    proj_kernel<<<M_/4, 256, 0, stream>>>(X, proj_w, PRED);

    nnmin_kernel<<<dim3(N_/256, B_), 256, 0, stream>>>(PRED, CENT, RMA);
    nnmin_kernel<<<dim3(N_/256, B_), 256, 0, stream>>>(CENT, PRED, RMB);
    knn_kernel<<<dim3(N_/256, B_), 256, 0, stream>>>(PRED, MEAND);
    kl_kernel<<<B_, 256, 0, stream>>>(MEAND, KLB);
    final_kernel<<<1, 256, 0, stream>>>(RMA, RMB, KLB, out);
}

// Round 11
// 4167.424 us; speedup vs baseline: 1.1092x; 1.0375x over previous
//
#include <hip/hip_runtime.h>
#include <math.h>

// Problem constants (GridSmoother)
#define B_   16
#define P_   8192
#define N_   1024
#define D_   384
#define L_   12
#define H_   6
#define HD_  64
#define M_   (B_*N_)     // 16384 rows
#define DQKV_ (3*D_)     // 1152
#define DH_   (4*D_)     // 1536

typedef unsigned short ushort_t;
typedef unsigned long long u64_t;
typedef __attribute__((ext_vector_type(8))) short short8;
typedef __attribute__((ext_vector_type(4))) float floatx4;
typedef __attribute__((ext_vector_type(2))) float floatx2;

// bf16 helpers (RNE), raw-bits representation
__device__ __forceinline__ ushort_t f2bf(float f) {
    unsigned u = __float_as_uint(f);
    unsigned rounding = 0x7fffu + ((u >> 16) & 1u);
    return (ushort_t)((u + rounding) >> 16);
}
__device__ __forceinline__ float bf2f(ushort_t u) {
    return __uint_as_float(((unsigned)u) << 16);
}

// DPP lane-exchange on f32 (returns partner's value)
template<int CTRL>
__device__ __forceinline__ float dpp_mov_f(float x) {
    int i = __float_as_int(x);
    i = __builtin_amdgcn_update_dpp(i, i, CTRL, 0xF, 0xF, false);
    return __int_as_float(i);
}

// ---------------------------------------------------------------------------
// Embed: X[m,d] = sum_k grid[m,k] * ew[k,d]   (K=3)
__global__ __launch_bounds__(D_) void embed_kernel(const float* __restrict__ g,
                                                   const float* __restrict__ ew,
                                                   float* __restrict__ X) {
    int m = blockIdx.x;
    int d = threadIdx.x;
    float g0 = g[m*3+0], g1 = g[m*3+1], g2 = g[m*3+2];
    X[(size_t)m*D_ + d] = g0*ew[0*D_+d] + g1*ew[1*D_+d] + g2*ew[2*D_+d];
}

// ---------------------------------------------------------------------------
// Weight transpose-cast: W [L][K][N] f32 -> Wt [L][N][K] bf16 bits
__global__ __launch_bounds__(256) void transcast_kernel(const float* __restrict__ W,
                                                        ushort_t* __restrict__ Wt,
                                                        int K, int Nc) {
    __shared__ float t[32][33];
    const float* Wl = W + (size_t)blockIdx.z*K*Nc;
    ushort_t* Wtl = Wt + (size_t)blockIdx.z*K*Nc;
    int n0 = blockIdx.x*32, k0 = blockIdx.y*32;
    int tx = threadIdx.x & 31, ty = threadIdx.x >> 5;   // 32 x 8
#pragma unroll
    for (int j = 0; j < 32; j += 8)
        t[ty+j][tx] = Wl[(size_t)(k0+ty+j)*Nc + n0+tx];
    __syncthreads();
#pragma unroll
    for (int j = 0; j < 32; j += 8)
        Wtl[(size_t)(n0+ty+j)*K + k0+tx] = f2bf(t[tx][ty+j]);
}

// ---------------------------------------------------------------------------
// LayerNorm: one wave per row of 384; reads f32 X, writes bf16 bits.
__global__ __launch_bounds__(256) void ln_kernel(const float* __restrict__ Xin,
                                                 const float* __restrict__ w,
                                                 const float* __restrict__ bvec,
                                                 ushort_t* __restrict__ out) {
    int wid = threadIdx.x >> 6, lane = threadIdx.x & 63;
    int row = blockIdx.x*4 + wid;
    const float* xr = Xin + (size_t)row*D_;
    float v[6];
#pragma unroll
    for (int i = 0; i < 6; i++) v[i] = xr[lane + i*64];
    float s = 0.f;
#pragma unroll
    for (int i = 0; i < 6; i++) s += v[i];
#pragma unroll
    for (int off = 32; off; off >>= 1) s += __shfl_xor(s, off, 64);
    float mean = s * (1.0f/(float)D_);
    float vs = 0.f;
#pragma unroll
    for (int i = 0; i < 6; i++) { float d = v[i]-mean; vs += d*d; }
#pragma unroll
    for (int off = 32; off; off >>= 1) vs += __shfl_xor(vs, off, 64);
    float var = vs * (1.0f/(float)D_);
    float rstd = 1.0f / sqrtf(var + 1e-5f);
    ushort_t* orow = out + (size_t)row*D_;
#pragma unroll
    for (int i = 0; i < 6; i++) {
        int e = lane + i*64;
        orow[e] = f2bf((v[i]-mean)*rstd*w[e] + bvec[e]);
    }
}

// ---------------------------------------------------------------------------
__device__ __forceinline__ float gelu_f(float x) {
    const float c = 0.7978845608028654f;   // sqrt(2/pi)
    float x3 = x*x*x;
    return 0.5f*x*(1.0f + tanhf(c*(x + 0.044715f*x3)));
}

// ---------------------------------------------------------------------------
// MFMA bf16 GEMM v2 (R5 configuration — LDS stride 32, 16B-aligned b128):
// register-prefetch staging, vectorized epilogues.
// EPI: 0 = bias -> bf16 out; 1 = bias + residual add into f32 C;
//      2 = gelu(bias+acc) -> bf16 out;
//      3 = QKV split: cols<768 packed bf16, cols>=768 scatter to VT.
template<int EPI>
__global__ __launch_bounds__(256) void mfma_gemm(const ushort_t* __restrict__ A,
                                                 const ushort_t* __restrict__ Wt,
                                                 const float* __restrict__ bias,
                                                 void* __restrict__ Cout,
                                                 ushort_t* __restrict__ VT,
                                                 int K, int Nc) {
    __shared__ __attribute__((aligned(16))) ushort_t smem[2*128*32];   // 16 KB
    ushort_t* smA = smem;
    ushort_t* smB = smem + 128*32;
    int tid = threadIdx.x;
    int lane = tid & 63, w = tid >> 6;
    int wm = w >> 1, wn = w & 1;
    int L = lane & 15, G = lane >> 4;
    int rowBase = blockIdx.y * 128, colBase = blockIdx.x * 128;

    floatx4 acc[4][4];
#pragma unroll
    for (int i = 0; i < 4; i++)
#pragma unroll
        for (int j = 0; j < 4; j++) acc[i][j] = (floatx4){0.f,0.f,0.f,0.f};

    // staging map: 256 threads x 2 chunks per buffer; chunk = 16B = 8 bf16
    int sr = tid >> 2;          // row 0..63 (and +64)
    int kc = tid & 3;           // k-chunk 0..3
    const ushort_t* Ag = A  + (size_t)(rowBase + sr)*K + kc*8;
    const ushort_t* Bg = Wt + (size_t)(colBase + sr)*K + kc*8;
    size_t step64 = (size_t)64*K;

    short8 ra0, ra1, rb0, rb1;
    ra0 = *(const short8*)(Ag);
    ra1 = *(const short8*)(Ag + step64);
    rb0 = *(const short8*)(Bg);
    rb1 = *(const short8*)(Bg + step64);

    for (int k0 = 0; k0 < K; k0 += 32) {
        __syncthreads();
        *(short8*)(smA + sr*32 + kc*8)        = ra0;
        *(short8*)(smA + (64+sr)*32 + kc*8)   = ra1;
        *(short8*)(smB + sr*32 + kc*8)        = rb0;
        *(short8*)(smB + (64+sr)*32 + kc*8)   = rb1;
        __syncthreads();
        if (k0 + 32 < K) {      // prefetch next k-slab; loads stay in flight
            ra0 = *(const short8*)(Ag + k0 + 32);
            ra1 = *(const short8*)(Ag + step64 + k0 + 32);
            rb0 = *(const short8*)(Bg + k0 + 32);
            rb1 = *(const short8*)(Bg + step64 + k0 + 32);
        }
        short8 af[4], bfr[4];
#pragma unroll
        for (int t = 0; t < 4; t++) {
            af[t]  = *(const short8*)(smA + (wm*64 + t*16 + L)*32 + G*8);
            bfr[t] = *(const short8*)(smB + (wn*64 + t*16 + L)*32 + G*8);
        }
#pragma unroll
        for (int mt = 0; mt < 4; mt++)
#pragma unroll
            for (int nt = 0; nt < 4; nt++)
                acc[mt][nt] = __builtin_amdgcn_mfma_f32_16x16x32_bf16(
                    af[mt], bfr[nt], acc[mt][nt], 0, 0, 0);
        __syncthreads();
    }

    __syncthreads();   // smem reuse for epilogue

    if (EPI == 3 && colBase >= 2*D_) {
        // pure-V column block: scalar scatter into VT[b,h,d,n]
        int cBase = colBase + wn*64 + L;
        int rBase = rowBase + wm*64 + G*4;
#pragma unroll
        for (int nt = 0; nt < 4; nt++) {
            int col = cBase + nt*16;
            float bv = bias[col];
            int hh = (col - 2*D_) >> 6, d = (col - 2*D_) & 63;
#pragma unroll
            for (int mt = 0; mt < 4; mt++) {
#pragma unroll
                for (int r = 0; r < 4; r++) {
                    int row = rBase + mt*16 + r;
                    int b = row >> 10, n = row & 1023;
                    VT[(((size_t)b*H_ + hh)*64 + d)*N_ + n] = f2bf(acc[mt][nt][r] + bv);
                }
            }
        }
    } else if (EPI == 1) {
        // f32 residual add, vectorized via per-wave LDS slab (16x64 f32)
        float* fs = (float*)smem + w*1024;
        int orow = lane >> 2, c4 = lane & 3;
#pragma unroll
        for (int mt = 0; mt < 4; mt++) {
#pragma unroll
            for (int nt = 0; nt < 4; nt++) {
                float bv = bias[colBase + wn*64 + nt*16 + L];
#pragma unroll
                for (int r = 0; r < 4; r++)
                    fs[(G*4+r)*64 + nt*16 + L] = acc[mt][nt][r] + bv;
            }
            float* og = (float*)Cout + (size_t)(rowBase + wm*64 + mt*16 + orow)*Nc
                        + colBase + wn*64;
#pragma unroll
            for (int kk = 0; kk < 4; kk++) {
                float4 sv = *(float4*)(fs + orow*64 + kk*16 + c4*4);
                float4 gv = *(float4*)(og + kk*16 + c4*4);
                gv.x += sv.x; gv.y += sv.y; gv.z += sv.z; gv.w += sv.w;
                *(float4*)(og + kk*16 + c4*4) = gv;
            }
        }
    } else {
        // bf16 out (EPI 0/2/3-QK), vectorized via per-wave LDS slab (stride 72)
        ushort_t* us = smem + w*1152;
        int orow = lane >> 2, oc = lane & 3;
#pragma unroll
        for (int mt = 0; mt < 4; mt++) {
#pragma unroll
            for (int nt = 0; nt < 4; nt++) {
                float bv = bias[colBase + wn*64 + nt*16 + L];
#pragma unroll
                for (int r = 0; r < 4; r++) {
                    float v = acc[mt][nt][r] + bv;
                    if (EPI == 2) v = gelu_f(v);
                    us[(G*4+r)*72 + nt*16 + L] = f2bf(v);
                }
            }
            short8 o0 = *(short8*)(us + orow*72 + oc*8);
            short8 o1 = *(short8*)(us + orow*72 + 32 + oc*8);
            ushort_t* og = (ushort_t*)Cout + (size_t)(rowBase + wm*64 + mt*16 + orow)*Nc
                           + colBase + wn*64;
            *(short8*)(og + oc*8) = o0;
            *(short8*)(og + 32 + oc*8) = o1;
        }
    }
}

// ---------------------------------------------------------------------------
// Flash attention v3: softmax 16-lane reductions via pure-VALU DPP butterfly
// (bit-exact xor-equivalents; R10 change). xor1=quad_perm[1,0,3,2],
// xor2=quad_perm[2,3,0,1]; after those levels each quad is bit-uniform so
// row_half_mirror (lane^7) delivers the xor4 partner's bits, and after that
// each 8-half is uniform so row_mirror (lane^15) delivers xor8's bits.
// Replaces 32 ds_bpermute (2 dependent 4-level DS chains) per k-tile with
// pipelined VALU DPP ops. LPAD 72 elements = 144 B (16B-aligned for b128).
#define LPAD 72
__global__ __launch_bounds__(256) void fattn_kernel(const ushort_t* __restrict__ QKV,
                                                    const ushort_t* __restrict__ VT,
                                                    ushort_t* __restrict__ O) {
    __shared__ __attribute__((aligned(16))) ushort_t Ks[64*LPAD];
    __shared__ __attribute__((aligned(16))) ushort_t Vs[64*LPAD];
    __shared__ __attribute__((aligned(16))) ushort_t Pw[4*16*LPAD];
    int b = blockIdx.z, h = blockIdx.y;
    int qBase = blockIdx.x * 64;
    int tid = threadIdx.x;
    int lane = tid & 63, w = tid >> 6;
    int L = lane & 15, G = lane >> 4;

    short8 qf[2];
    {
        const ushort_t* qp = QKV + ((size_t)(b*N_ + qBase + w*16 + L))*DQKV_ + h*HD_ + G*8;
        qf[0] = *(const short8*)(qp);
        qf[1] = *(const short8*)(qp + 32);
    }

    floatx4 oacc[4];
#pragma unroll
    for (int nt = 0; nt < 4; nt++) oacc[nt] = (floatx4){0.f,0.f,0.f,0.f};
    float mrow[4], lrow[4];
#pragma unroll
    for (int r = 0; r < 4; r++) { mrow[r] = -3.0e38f; lrow[r] = 0.f; }

    ushort_t* pw = Pw + w*16*LPAD;
    const ushort_t* Kbase = QKV + (size_t)b*N_*DQKV_ + D_ + h*HD_;
    const ushort_t* Vbase = VT + ((size_t)b*H_ + h)*64*N_;

    // staging map: 512 chunks (16B) per buffer; thread covers chunk tid and tid+256
    int srow = tid >> 3;         // 0..31 (and +32)
    int dc   = tid & 7;
    const ushort_t* Kg0 = Kbase + (size_t)srow*DQKV_ + dc*8;
    const ushort_t* Kg1 = Kbase + (size_t)(srow+32)*DQKV_ + dc*8;
    const ushort_t* Vg0 = Vbase + (size_t)srow*N_ + dc*8;       // srow = d-row for V
    const ushort_t* Vg1 = Vbase + (size_t)(srow+32)*N_ + dc*8;

    short8 rk0, rk1, rv0, rv1;
    rk0 = *(const short8*)(Kg0);
    rk1 = *(const short8*)(Kg1);
    rv0 = *(const short8*)(Vg0);
    rv1 = *(const short8*)(Vg1);

    for (int kt = 0; kt < N_/64; kt++) {
        __syncthreads();   // prior tile's PV reads of Ks/Vs complete
        *(short8*)(Ks + srow*LPAD + dc*8)       = rk0;
        *(short8*)(Ks + (srow+32)*LPAD + dc*8)  = rk1;
        *(short8*)(Vs + srow*LPAD + dc*8)       = rv0;
        *(short8*)(Vs + (srow+32)*LPAD + dc*8)  = rv1;
        __syncthreads();
        if (kt + 1 < N_/64) {   // prefetch next tile (in flight across compute)
            rk0 = *(const short8*)(Kg0 + (size_t)(kt+1)*64*DQKV_);
            rk1 = *(const short8*)(Kg1 + (size_t)(kt+1)*64*DQKV_);
            rv0 = *(const short8*)(Vg0 + (kt+1)*64);
            rv1 = *(const short8*)(Vg1 + (kt+1)*64);
        }

        // S = Q K^T  (16 q-rows x 64 keys per wave)
        floatx4 sc[4];
#pragma unroll
        for (int ct = 0; ct < 4; ct++) sc[ct] = (floatx4){0.f,0.f,0.f,0.f};
#pragma unroll
        for (int ks = 0; ks < 2; ks++)
#pragma unroll
            for (int ct = 0; ct < 4; ct++) {
                short8 bf = *(const short8*)(Ks + (ct*16 + L)*LPAD + ks*32 + G*8);
                sc[ct] = __builtin_amdgcn_mfma_f32_16x16x32_bf16(qf[ks], bf, sc[ct], 0, 0, 0);
            }

        // online softmax over this 64-key tile
        float rmax[4], rsum[4];
#pragma unroll
        for (int r = 0; r < 4; r++) {
#pragma unroll
            for (int ct = 0; ct < 4; ct++) sc[ct][r] *= 0.125f;
            rmax[r] = fmaxf(fmaxf(sc[0][r], sc[1][r]), fmaxf(sc[2][r], sc[3][r]));
        }
        // 16-lane max reduce via DPP (bit-exact vs shfl_xor 1,2,4,8)
#pragma unroll
        for (int r = 0; r < 4; r++) {
            rmax[r] = fmaxf(rmax[r], dpp_mov_f<0xB1>(rmax[r]));   // xor 1
            rmax[r] = fmaxf(rmax[r], dpp_mov_f<0x4E>(rmax[r]));   // xor 2
            rmax[r] = fmaxf(rmax[r], dpp_mov_f<0x141>(rmax[r]));  // xor 4 (half_mirror)
            rmax[r] = fmaxf(rmax[r], dpp_mov_f<0x140>(rmax[r]));  // xor 8 (mirror)
        }
        float corr[4];
#pragma unroll
        for (int r = 0; r < 4; r++) {
            float mn = fmaxf(mrow[r], rmax[r]);
            corr[r] = __expf(mrow[r] - mn);
            mrow[r] = mn;
            rsum[r] = 0.f;
#pragma unroll
            for (int ct = 0; ct < 4; ct++) {
                float p = __expf(sc[ct][r] - mn);
                sc[ct][r] = p;
                rsum[r] += p;
            }
        }
        // 16-lane sum reduce via DPP (bit-exact: same ascending xor order,
        // mirror levels deliver bit-identical partner values by uniformity)
#pragma unroll
        for (int r = 0; r < 4; r++) {
            rsum[r] += dpp_mov_f<0xB1>(rsum[r]);
            rsum[r] += dpp_mov_f<0x4E>(rsum[r]);
            rsum[r] += dpp_mov_f<0x141>(rsum[r]);
            rsum[r] += dpp_mov_f<0x140>(rsum[r]);
        }
#pragma unroll
        for (int r = 0; r < 4; r++) lrow[r] = lrow[r]*corr[r] + rsum[r];

        // P (C-layout) -> wave-private LDS -> A-layout (in-wave ordering, no barrier)
#pragma unroll
        for (int ct = 0; ct < 4; ct++)
#pragma unroll
            for (int r = 0; r < 4; r++)
                pw[(G*4 + r)*LPAD + ct*16 + L] = f2bf(sc[ct][r]);
#pragma unroll
        for (int nt = 0; nt < 4; nt++)
#pragma unroll
            for (int r = 0; r < 4; r++) oacc[nt][r] *= corr[r];

        // O += P V
#pragma unroll
        for (int ks = 0; ks < 2; ks++) {
            short8 pf = *(const short8*)(pw + L*LPAD + ks*32 + G*8);
#pragma unroll
            for (int nt = 0; nt < 4; nt++) {
                short8 vf = *(const short8*)(Vs + (nt*16 + L)*LPAD + ks*32 + G*8);
                oacc[nt] = __builtin_amdgcn_mfma_f32_16x16x32_bf16(pf, vf, oacc[nt], 0, 0, 0);
            }
        }
    }

    // normalized O through wave-private pw slab -> vector global store
    float inv[4];
#pragma unroll
    for (int r = 0; r < 4; r++) inv[r] = 1.0f / lrow[r];
#pragma unroll
    for (int nt = 0; nt < 4; nt++)
#pragma unroll
        for (int r = 0; r < 4; r++)
            pw[(G*4 + r)*LPAD + nt*16 + L] = f2bf(oacc[nt][r]*inv[r]);
    int orow = lane >> 2, oc = lane & 3;
    short8 o0 = *(short8*)(pw + orow*LPAD + oc*8);
    short8 o1 = *(short8*)(pw + orow*LPAD + 32 + oc*8);
    ushort_t* og = O + (size_t)(b*N_ + qBase + w*16 + orow)*D_ + h*HD_;
    *(short8*)(og + oc*8) = o0;
    *(short8*)(og + 32 + oc*8) = o1;
}

// ---------------------------------------------------------------------------
// Final projection v2: one wave per row (coalesced); pred[m,c] = X[m,:] @ pw[:,c]
__global__ __launch_bounds__(256) void proj_kernel(const float* __restrict__ X,
                                                   const float* __restrict__ pw,
                                                   float* __restrict__ pred) {
    int wid = threadIdx.x >> 6, lane = threadIdx.x & 63;
    int m = blockIdx.x*4 + wid;
    const float* xr = X + (size_t)m*D_;
    float a0 = 0.f, a1 = 0.f, a2 = 0.f;
#pragma unroll
    for (int i = 0; i < 6; i++) {
        int k = lane + i*64;
        float xv = xr[k];
        a0 += xv*pw[k*3+0]; a1 += xv*pw[k*3+1]; a2 += xv*pw[k*3+2];
    }
#pragma unroll
    for (int off = 32; off; off >>= 1) {
        a0 += __shfl_xor(a0, off, 64);
        a1 += __shfl_xor(a1, off, 64);
        a2 += __shfl_xor(a2, off, 64);
    }
    if (lane == 0) {
        pred[m*3+0] = a0; pred[m*3+1] = a1; pred[m*3+2] = a2;
    }
}

// ---------------------------------------------------------------------------
// FPS v7 (kept from R10: 926 us ≈ v5's 918 floor; structure is
// latency-chain-bound, wave count 4 is at the measured flat region).
// 256 threads (4 waves, 1/SIMD), 32 pts/thread, packed v_pk math (bit-exact),
// LDS-buffered centers, 16-slot merge: one slot read + 4 DPP levels.
// Tie-break exact: u64 (dist_bits<<32)|~(bj*256+t), max-reduce.
template<int CTRL>
__device__ __forceinline__ u64_t dpp_max64(u64_t x) {
    unsigned lo = (unsigned)x;
    unsigned hi = (unsigned)(x >> 32);
    lo = (unsigned)__builtin_amdgcn_update_dpp((int)lo, (int)lo, CTRL, 0xF, 0xF, false);
    hi = (unsigned)__builtin_amdgcn_update_dpp((int)hi, (int)hi, CTRL, 0xF, 0xF, false);
    u64_t o = ((u64_t)hi << 32) | lo;
    return (o > x) ? o : x;
}
__device__ __forceinline__ floatx2 pk_sub(floatx2 a, floatx2 b) {
    floatx2 r;
    asm("v_pk_add_f32 %0, %1, %2 neg_lo:[0,1] neg_hi:[0,1]" : "=v"(r) : "v"(a), "v"(b));
    return r;
}
__device__ __forceinline__ floatx2 pk_mul(floatx2 a, floatx2 b) {
    floatx2 r;
    asm("v_pk_mul_f32 %0, %1, %2" : "=v"(r) : "v"(a), "v"(b));
    return r;
}
__device__ __forceinline__ floatx2 pk_add(floatx2 a, floatx2 b) {
    floatx2 r;
    asm("v_pk_add_f32 %0, %1, %2" : "=v"(r) : "v"(a), "v"(b));
    return r;
}

__global__ __launch_bounds__(256) void fps_kernel(const float* __restrict__ pts,
                                                  float* __restrict__ centers) {
    __shared__ float Lx[P_], Ly[P_], Lz[P_];            // 96 KiB
    __shared__ float Cbuf[N_*3];                        // 12 KiB (centers staging)
    __shared__ u64_t slot[2][16];
    int b = blockIdx.x, t = threadIdx.x;
    const float* pb = pts + (size_t)b*P_*3;
    floatx2 px[16], py[16], pz[16];
    float dist[32];
#pragma unroll
    for (int j = 0; j < 32; j++) {
        int p = j*256 + t;
        float x = pb[p*3+0], y = pb[p*3+1], z = pb[p*3+2];
        Lx[p] = x; Ly[p] = y; Lz[p] = z;
        px[j>>1][j&1] = x; py[j>>1][j&1] = y; pz[j>>1][j&1] = z;
        dist[j] = 1e10f;
    }
    int winner = 0;
    __syncthreads();
    for (int it = 0; it < N_; it++) {
        float lx = Lx[winner], ly = Ly[winner], lz = Lz[winner];
        if (t == 0) {
            Cbuf[it*3+0] = lx; Cbuf[it*3+1] = ly; Cbuf[it*3+2] = lz;
        }
        floatx2 lx2 = {lx, lx}, ly2 = {ly, ly}, lz2 = {lz, lz};
        // per-thread best: strict > with ascending j == smallest index on ties
        float bd = -1.0f; int bj = 0;
#pragma unroll
        for (int jj = 0; jj < 16; jj++) {
            floatx2 dx = pk_sub(px[jj], lx2);
            floatx2 dy = pk_sub(py[jj], ly2);
            floatx2 dz = pk_sub(pz[jj], lz2);
            // exact order: (dx*dx + dy*dy) + dz*dz, all RN, no contraction
            floatx2 d2 = pk_add(pk_add(pk_mul(dx,dx), pk_mul(dy,dy)), pk_mul(dz,dz));
            float d0 = fminf(dist[2*jj+0], d2[0]);
            dist[2*jj+0] = d0;
            bool g0 = d0 > bd; bd = g0 ? d0 : bd; bj = g0 ? 2*jj+0 : bj;
            float d1 = fminf(dist[2*jj+1], d2[1]);
            dist[2*jj+1] = d1;
            bool g1 = d1 > bd; bd = g1 ? d1 : bd; bj = g1 ? 2*jj+1 : bj;
        }
        // pack once: global idx p = bj*256 + t (ascending in j), ~p -> first-wins
        u64_t best = ((u64_t)__float_as_uint(bd) << 32)
                   | (unsigned)(~(unsigned)((bj<<8) + t));
        // in-row (16-lane) argmax, pure VALU
        best = dpp_max64<0xB1>(best);    // quad_perm [1,0,3,2] : xor 1
        best = dpp_max64<0x4E>(best);    // quad_perm [2,3,0,1] : xor 2
        best = dpp_max64<0x124>(best);   // row_ror:4
        best = dpp_max64<0x128>(best);   // row_ror:8
        int par = it & 1;
        if ((t & 15) == 0) slot[par][t >> 4] = best;   // 16 row maxima (4 waves x 4 rows)
        __syncthreads();
        // cross-row merge: one slot per lane, 4 DPP levels -> global max in all lanes
        u64_t v = slot[par][t & 15];
        v = dpp_max64<0xB1>(v);
        v = dpp_max64<0x4E>(v);
        v = dpp_max64<0x124>(v);
        v = dpp_max64<0x128>(v);
        winner = (int)(~(unsigned)(v & 0xFFFFFFFFull));
    }
    __syncthreads();
    // coalesced centers flush (3072 floats, 12 per thread)
    float* cb = centers + (size_t)b*N_*3;
#pragma unroll
    for (int i = 0; i < 12; i++) cb[t + i*256] = Cbuf[t + i*256];
}

// ---------------------------------------------------------------------------
__global__ __launch_bounds__(256) void nnmin_kernel(const float* __restrict__ Asrc,
                                                    const float* __restrict__ Bsrc,
                                                    float* __restrict__ outmin) {
    int b = blockIdx.y;
    int i = blockIdx.x*256 + threadIdx.x;
    __shared__ float tile[256][3];
    const float* ar = Asrc + ((size_t)b*N_ + i)*3;
    float ax = ar[0], ay = ar[1], az = ar[2];
    float best = 3.0e38f;
    for (int j0 = 0; j0 < N_; j0 += 256) {
        __syncthreads();
        const float* br = Bsrc + ((size_t)b*N_ + j0 + threadIdx.x)*3;
        tile[threadIdx.x][0] = br[0]; tile[threadIdx.x][1] = br[1]; tile[threadIdx.x][2] = br[2];
        __syncthreads();
        for (int j = 0; j < 256; j++) {
            float dx = ax - tile[j][0], dy = ay - tile[j][1], dz = az - tile[j][2];
            float d = dx*dx + dy*dy + dz*dz;
            best = fminf(best, d);
        }
    }
    outmin[(size_t)b*N_ + i] = sqrtf(best);
}

__global__ __launch_bounds__(256) void knn_kernel(const float* __restrict__ Pp,
                                                  float* __restrict__ mean_d) {
    int b = blockIdx.y;
    int i = blockIdx.x*256 + threadIdx.x;
    __shared__ float tile[256][3];
    const float* ar = Pp + ((size_t)b*N_ + i)*3;
    float ax = ar[0], ay = ar[1], az = ar[2];
    float s[6];
#pragma unroll
    for (int q = 0; q < 6; q++) s[q] = 3.0e38f;
    for (int j0 = 0; j0 < N_; j0 += 256) {
        __syncthreads();
        const float* br = Pp + ((size_t)b*N_ + j0 + threadIdx.x)*3;
        tile[threadIdx.x][0] = br[0]; tile[threadIdx.x][1] = br[1]; tile[threadIdx.x][2] = br[2];
        __syncthreads();
        for (int j = 0; j < 256; j++) {
            float dx = ax - tile[j][0], dy = ay - tile[j][1], dz = az - tile[j][2];
            float d = dx*dx + dy*dy + dz*dz;
            if (d < s[5]) {
                s[5] = d;
#pragma unroll
                for (int q = 5; q > 0; q--)
                    if (s[q] < s[q-1]) { float tmp = s[q]; s[q] = s[q-1]; s[q-1] = tmp; }
            }
        }
    }
    float msum = sqrtf(s[1]) + sqrtf(s[2]) + sqrtf(s[3]) + sqrtf(s[4]) + sqrtf(s[5]);
    mean_d[(size_t)b*N_ + i] = msum * 0.2f;
}

__global__ __launch_bounds__(256) void kl_kernel(const float* __restrict__ md,
                                                 float* __restrict__ klb) {
    int b = blockIdx.x, t = threadIdx.x;
    const float* row = md + (size_t)b*N_;
    float v[4];
#pragma unroll
    for (int i = 0; i < 4; i++) v[i] = row[t + i*256];
    float mx = fmaxf(fmaxf(v[0], v[1]), fmaxf(v[2], v[3]));
#pragma unroll
    for (int off = 32; off; off >>= 1) mx = fmaxf(mx, __shfl_xor(mx, off, 64));
    __shared__ float redm[4], rse[4], rsx[4];
    int wid = t >> 6, lane = t & 63;
    if (lane == 0) redm[wid] = mx;
    __syncthreads();
    mx = fmaxf(fmaxf(redm[0], redm[1]), fmaxf(redm[2], redm[3]));
    float se = 0.f, sx = 0.f;
#pragma unroll
    for (int i = 0; i < 4; i++) { se += expf(v[i]-mx); sx += v[i]; }
#pragma unroll
    for (int off = 32; off; off >>= 1) { se += __shfl_xor(se, off, 64); sx += __shfl_xor(sx, off, 64); }
    if (lane == 0) { rse[wid] = se; rsx[wid] = sx; }
    __syncthreads();
    if (t == 0) {
        float SE = rse[0]+rse[1]+rse[2]+rse[3];
        float SX = rsx[0]+rsx[1]+rsx[2]+rsx[3];
        klb[b] = mx + logf(SE) - SX*(1.0f/(float)N_) - logf((float)N_);
    }
}

__global__ __launch_bounds__(256) void final_kernel(const float* __restrict__ rma,
                                                    const float* __restrict__ rmb,
                                                    const float* __restrict__ klb,
                                                    float* __restrict__ out) {
    int t = threadIdx.x;
    float s = 0.f;
    for (int i = t; i < B_*N_; i += 256) s += rma[i] + rmb[i];
#pragma unroll
    for (int off = 32; off; off >>= 1) s += __shfl_xor(s, off, 64);
    __shared__ float red[4];
    int wid = t >> 6, lane = t & 63;
    if (lane == 0) red[wid] = s;
    __syncthreads();
    if (t == 0) {
        float S = red[0]+red[1]+red[2]+red[3];
        out[0] = 0.5f*S/(float)(B_*N_);
        out[1] = 0.f;
        float K = 0.f;
        for (int b = 0; b < B_; b++) K += klb[b];
        out[1] = K/(float)B_;
    }
}

// ---------------------------------------------------------------------------
extern "C" void kernel_launch(void* const* d_in, const int* in_sizes, int n_in,
                              void* d_out, int out_size, void* d_ws, size_t ws_size,
                              hipStream_t stream) {
    (void)in_sizes; (void)n_in; (void)out_size; (void)ws_size;
    const float* pts     = (const float*)d_in[0];
    const float* grid    = (const float*)d_in[1];
    const float* embed_w = (const float*)d_in[2];
    const float* proj_w  = (const float*)d_in[3];
    const float* ln1_w   = (const float*)d_in[4];
    const float* ln1_b   = (const float*)d_in[5];
    const float* qkv_w   = (const float*)d_in[6];
    const float* qkv_b   = (const float*)d_in[7];
    const float* attn_w  = (const float*)d_in[8];
    const float* attn_b  = (const float*)d_in[9];
    const float* ln2_w   = (const float*)d_in[10];
    const float* ln2_b   = (const float*)d_in[11];
    const float* mlp_w1  = (const float*)d_in[12];
    const float* mlp_b1  = (const float*)d_in[13];
    const float* mlp_w2  = (const float*)d_in[14];
    const float* mlp_b2  = (const float*)d_in[15];
    float* out = (float*)d_out;

    // workspace layout (~144 MB)
    float*    X     = (float*)d_ws;                         // M*D f32
    ushort_t* Hb16  = (ushort_t*)(X + (size_t)M_*D_);       // M*D bf16
    ushort_t* BIG16 = Hb16 + (size_t)M_*D_;                 // M*1536 bf16 (QKV / MLP hidden)
    ushort_t* VT    = BIG16 + (size_t)M_*DH_;               // B*H*64*N bf16 (V transposed)
    ushort_t* WQ    = VT  + (size_t)B_*H_*HD_*N_;           // L*1152*384
    ushort_t* WA    = WQ  + (size_t)L_*DQKV_*D_;            // L*384*384
    ushort_t* WM1   = WA  + (size_t)L_*D_*D_;               // L*1536*384
    ushort_t* WM2   = WM1 + (size_t)L_*DH_*D_;              // L*384*1536
    float*    PRED  = (float*)(WM2 + (size_t)L_*D_*DH_);    // M*3
    float*    CENT  = PRED + (size_t)M_*3;                  // B*N*3
    float*    RMA   = CENT + (size_t)B_*N_*3;               // B*N
    float*    RMB   = RMA  + (size_t)B_*N_;                 // B*N
    float*    MEAND = RMB  + (size_t)B_*N_;                 // B*N
    float*    KLB   = MEAND + (size_t)B_*N_;                // B

    // one-time weight transpose-casts (f32 [K,N] -> bf16 [N,K])
    transcast_kernel<<<dim3(DQKV_/32, D_/32,  L_), 256, 0, stream>>>(qkv_w,  WQ,  D_,  DQKV_);
    transcast_kernel<<<dim3(D_/32,    D_/32,  L_), 256, 0, stream>>>(attn_w, WA,  D_,  D_);
    transcast_kernel<<<dim3(DH_/32,   D_/32,  L_), 256, 0, stream>>>(mlp_w1, WM1, D_,  DH_);
    transcast_kernel<<<dim3(D_/32,    DH_/32, L_), 256, 0, stream>>>(mlp_w2, WM2, DH_, D_);

    // FPS (independent of transformer)
    fps_kernel<<<B_, 256, 0, stream>>>(pts, CENT);

    embed_kernel<<<M_, D_, 0, stream>>>(grid, embed_w, X);

    for (int l = 0; l < L_; l++) {
        ln_kernel<<<M_/4, 256, 0, stream>>>(X, ln1_w + l*D_, ln1_b + l*D_, Hb16);
        mfma_gemm<3><<<dim3(DQKV_/128, M_/128), 256, 0, stream>>>(
            Hb16, WQ + (size_t)l*DQKV_*D_, qkv_b + l*DQKV_, BIG16, VT, D_, DQKV_);
        fattn_kernel<<<dim3(N_/64, H_, B_), 256, 0, stream>>>(BIG16, VT, Hb16);
        mfma_gemm<1><<<dim3(D_/128, M_/128), 256, 0, stream>>>(
            Hb16, WA + (size_t)l*D_*D_, attn_b + l*D_, X, nullptr, D_, D_);
        ln_kernel<<<M_/4, 256, 0, stream>>>(X, ln2_w + l*D_, ln2_b + l*D_, Hb16);
        mfma_gemm<2><<<dim3(DH_/128, M_/128), 256, 0, stream>>>(
            Hb16, WM1 + (size_t)l*DH_*D_, mlp_b1 + l*DH_, BIG16, nullptr, D_, DH_);
        mfma_gemm<1><<<dim3(D_/128, M_/128), 256, 0, stream>>>(
            BIG16, WM2 + (size_t)l*D_*DH_, mlp_b2 + l*D_, X, nullptr, DH_, D_);
    }

    proj_kernel<<<M_/4, 256, 0, stream>>>(X, proj_w, PRED);

    nnmin_kernel<<<dim3(N_/256, B_), 256, 0, stream>>>(PRED, CENT, RMA);
    nnmin_kernel<<<dim3(N_/256, B_), 256, 0, stream>>>(CENT, PRED, RMB);
    knn_kernel<<<dim3(N_/256, B_), 256, 0, stream>>>(PRED, MEAND);
    kl_kernel<<<B_, 256, 0, stream>>>(MEAND, KLB);
    final_kernel<<<1, 256, 0, stream>>>(RMA, RMB, KLB, out);
}

// Round 12
// 4164.465 us; speedup vs baseline: 1.1100x; 1.0007x over previous
//
#include <hip/hip_runtime.h>
#include <math.h>

// Problem constants (GridSmoother)
#define B_   16
#define P_   8192
#define N_   1024
#define D_   384
#define L_   12
#define H_   6
#define HD_  64
#define M_   (B_*N_)     // 16384 rows
#define DQKV_ (3*D_)     // 1152
#define DH_   (4*D_)     // 1536

typedef unsigned short ushort_t;
typedef unsigned long long u64_t;
typedef __attribute__((ext_vector_type(8))) short short8;
typedef __attribute__((ext_vector_type(4))) float floatx4;
typedef __attribute__((ext_vector_type(2))) float floatx2;

// bf16 helpers (RNE), raw-bits representation
__device__ __forceinline__ ushort_t f2bf(float f) {
    unsigned u = __float_as_uint(f);
    unsigned rounding = 0x7fffu + ((u >> 16) & 1u);
    return (ushort_t)((u + rounding) >> 16);
}
__device__ __forceinline__ float bf2f(ushort_t u) {
    return __uint_as_float(((unsigned)u) << 16);
}

// DPP lane-exchange on f32 (returns partner's value)
template<int CTRL>
__device__ __forceinline__ float dpp_mov_f(float x) {
    int i = __float_as_int(x);
    i = __builtin_amdgcn_update_dpp(i, i, CTRL, 0xF, 0xF, false);
    return __int_as_float(i);
}

// ---------------------------------------------------------------------------
// Embed: X[m,d] = sum_k grid[m,k] * ew[k,d]   (K=3)
__global__ __launch_bounds__(D_) void embed_kernel(const float* __restrict__ g,
                                                   const float* __restrict__ ew,
                                                   float* __restrict__ X) {
    int m = blockIdx.x;
    int d = threadIdx.x;
    float g0 = g[m*3+0], g1 = g[m*3+1], g2 = g[m*3+2];
    X[(size_t)m*D_ + d] = g0*ew[0*D_+d] + g1*ew[1*D_+d] + g2*ew[2*D_+d];
}

// ---------------------------------------------------------------------------
// Weight transpose-cast: W [L][K][N] f32 -> Wt [L][N][K] bf16 bits
__global__ __launch_bounds__(256) void transcast_kernel(const float* __restrict__ W,
                                                        ushort_t* __restrict__ Wt,
                                                        int K, int Nc) {
    __shared__ float t[32][33];
    const float* Wl = W + (size_t)blockIdx.z*K*Nc;
    ushort_t* Wtl = Wt + (size_t)blockIdx.z*K*Nc;
    int n0 = blockIdx.x*32, k0 = blockIdx.y*32;
    int tx = threadIdx.x & 31, ty = threadIdx.x >> 5;   // 32 x 8
#pragma unroll
    for (int j = 0; j < 32; j += 8)
        t[ty+j][tx] = Wl[(size_t)(k0+ty+j)*Nc + n0+tx];
    __syncthreads();
#pragma unroll
    for (int j = 0; j < 32; j += 8)
        Wtl[(size_t)(n0+ty+j)*K + k0+tx] = f2bf(t[tx][ty+j]);
}

// ---------------------------------------------------------------------------
// LayerNorm: one wave per row of 384; reads f32 X, writes bf16 bits.
__global__ __launch_bounds__(256) void ln_kernel(const float* __restrict__ Xin,
                                                 const float* __restrict__ w,
                                                 const float* __restrict__ bvec,
                                                 ushort_t* __restrict__ out) {
    int wid = threadIdx.x >> 6, lane = threadIdx.x & 63;
    int row = blockIdx.x*4 + wid;
    const float* xr = Xin + (size_t)row*D_;
    float v[6];
#pragma unroll
    for (int i = 0; i < 6; i++) v[i] = xr[lane + i*64];
    float s = 0.f;
#pragma unroll
    for (int i = 0; i < 6; i++) s += v[i];
#pragma unroll
    for (int off = 32; off; off >>= 1) s += __shfl_xor(s, off, 64);
    float mean = s * (1.0f/(float)D_);
    float vs = 0.f;
#pragma unroll
    for (int i = 0; i < 6; i++) { float d = v[i]-mean; vs += d*d; }
#pragma unroll
    for (int off = 32; off; off >>= 1) vs += __shfl_xor(vs, off, 64);
    float var = vs * (1.0f/(float)D_);
    float rstd = 1.0f / sqrtf(var + 1e-5f);
    ushort_t* orow = out + (size_t)row*D_;
#pragma unroll
    for (int i = 0; i < 6; i++) {
        int e = lane + i*64;
        orow[e] = f2bf((v[i]-mean)*rstd*w[e] + bvec[e]);
    }
}

// ---------------------------------------------------------------------------
__device__ __forceinline__ float gelu_f(float x) {
    const float c = 0.7978845608028654f;   // sqrt(2/pi)
    float x3 = x*x*x;
    return 0.5f*x*(1.0f + tanhf(c*(x + 0.044715f*x3)));
}

// ---------------------------------------------------------------------------
// MFMA bf16 GEMM v3 (R12): BK=64, LDS row stride 72 (kills the stride-32
// 8-way bank conflict on ds_read_b128 fragment reads: banks {0,16} -> 8-bank
// spread, 2-way = free), 2 barriers per BK=64 step (was 3 per BK=32 step),
// 2-deep register prefetch. Accumulation order per acc[mt][nt] is unchanged
// (ascending 32-wide k-slabs) -> bit-exact vs v2.
// EPI: 0 = bias -> bf16 out; 1 = bias + residual add into f32 C;
//      2 = gelu(bias+acc) -> bf16 out;
//      3 = QKV split: cols<768 packed bf16, cols>=768 scatter to VT.
#define LDK 72
template<int EPI>
__global__ __launch_bounds__(256) void mfma_gemm(const ushort_t* __restrict__ A,
                                                 const ushort_t* __restrict__ Wt,
                                                 const float* __restrict__ bias,
                                                 void* __restrict__ Cout,
                                                 ushort_t* __restrict__ VT,
                                                 int K, int Nc) {
    __shared__ __attribute__((aligned(16))) ushort_t smem[2*128*LDK];   // 36 KB
    ushort_t* smA = smem;
    ushort_t* smB = smem + 128*LDK;
    int tid = threadIdx.x;
    int lane = tid & 63, w = tid >> 6;
    int wm = w >> 1, wn = w & 1;
    int L = lane & 15, G = lane >> 4;
    int rowBase = blockIdx.y * 128, colBase = blockIdx.x * 128;

    floatx4 acc[4][4];
#pragma unroll
    for (int i = 0; i < 4; i++)
#pragma unroll
        for (int j = 0; j < 4; j++) acc[i][j] = (floatx4){0.f,0.f,0.f,0.f};

    // staging map: 1024 chunks (16B = 8 bf16) per buffer; thread covers
    // chunks tid + i*256 (i=0..3): row = (tid>>3) + 32*i, col = (tid&7)*8
    int srow = tid >> 3;          // 0..31
    int scol = (tid & 7) * 8;     // 0..56
    const ushort_t* Ag = A  + (size_t)(rowBase + srow)*K + scol;
    const ushort_t* Bg = Wt + (size_t)(colBase + srow)*K + scol;
    size_t step32 = (size_t)32*K;

    short8 ra[4], rb[4];
#pragma unroll
    for (int i = 0; i < 4; i++) {
        ra[i] = *(const short8*)(Ag + step32*i);
        rb[i] = *(const short8*)(Bg + step32*i);
    }

    for (int k0 = 0; k0 < K; k0 += 64) {
        __syncthreads();   // prior step's fragment reads complete
#pragma unroll
        for (int i = 0; i < 4; i++) {
            *(short8*)(smA + (srow + 32*i)*LDK + scol) = ra[i];
            *(short8*)(smB + (srow + 32*i)*LDK + scol) = rb[i];
        }
        __syncthreads();
        if (k0 + 64 < K) {   // prefetch next BK=64 slab; loads stay in flight
#pragma unroll
            for (int i = 0; i < 4; i++) {
                ra[i] = *(const short8*)(Ag + step32*i + k0 + 64);
                rb[i] = *(const short8*)(Bg + step32*i + k0 + 64);
            }
        }
#pragma unroll
        for (int kk = 0; kk < 2; kk++) {
            short8 af[4], bfr[4];
#pragma unroll
            for (int t = 0; t < 4; t++) {
                af[t]  = *(const short8*)(smA + (wm*64 + t*16 + L)*LDK + kk*32 + G*8);
                bfr[t] = *(const short8*)(smB + (wn*64 + t*16 + L)*LDK + kk*32 + G*8);
            }
#pragma unroll
            for (int mt = 0; mt < 4; mt++)
#pragma unroll
                for (int nt = 0; nt < 4; nt++)
                    acc[mt][nt] = __builtin_amdgcn_mfma_f32_16x16x32_bf16(
                        af[mt], bfr[nt], acc[mt][nt], 0, 0, 0);
        }
    }

    __syncthreads();   // smem reuse for epilogue

    if (EPI == 3 && colBase >= 2*D_) {
        // pure-V column block: scalar scatter into VT[b,h,d,n]
        int cBase = colBase + wn*64 + L;
        int rBase = rowBase + wm*64 + G*4;
#pragma unroll
        for (int nt = 0; nt < 4; nt++) {
            int col = cBase + nt*16;
            float bv = bias[col];
            int hh = (col - 2*D_) >> 6, d = (col - 2*D_) & 63;
#pragma unroll
            for (int mt = 0; mt < 4; mt++) {
#pragma unroll
                for (int r = 0; r < 4; r++) {
                    int row = rBase + mt*16 + r;
                    int b = row >> 10, n = row & 1023;
                    VT[(((size_t)b*H_ + hh)*64 + d)*N_ + n] = f2bf(acc[mt][nt][r] + bv);
                }
            }
        }
    } else if (EPI == 1) {
        // f32 residual add, vectorized via per-wave LDS slab (16x64 f32)
        float* fs = (float*)smem + w*1024;
        int orow = lane >> 2, c4 = lane & 3;
#pragma unroll
        for (int mt = 0; mt < 4; mt++) {
#pragma unroll
            for (int nt = 0; nt < 4; nt++) {
                float bv = bias[colBase + wn*64 + nt*16 + L];
#pragma unroll
                for (int r = 0; r < 4; r++)
                    fs[(G*4+r)*64 + nt*16 + L] = acc[mt][nt][r] + bv;
            }
            float* og = (float*)Cout + (size_t)(rowBase + wm*64 + mt*16 + orow)*Nc
                        + colBase + wn*64;
#pragma unroll
            for (int kk = 0; kk < 4; kk++) {
                float4 sv = *(float4*)(fs + orow*64 + kk*16 + c4*4);
                float4 gv = *(float4*)(og + kk*16 + c4*4);
                gv.x += sv.x; gv.y += sv.y; gv.z += sv.z; gv.w += sv.w;
                *(float4*)(og + kk*16 + c4*4) = gv;
            }
        }
    } else {
        // bf16 out (EPI 0/2/3-QK), vectorized via per-wave LDS slab (stride 72)
        ushort_t* us = smem + w*1152;
        int orow = lane >> 2, oc = lane & 3;
#pragma unroll
        for (int mt = 0; mt < 4; mt++) {
#pragma unroll
            for (int nt = 0; nt < 4; nt++) {
                float bv = bias[colBase + wn*64 + nt*16 + L];
#pragma unroll
                for (int r = 0; r < 4; r++) {
                    float v = acc[mt][nt][r] + bv;
                    if (EPI == 2) v = gelu_f(v);
                    us[(G*4+r)*72 + nt*16 + L] = f2bf(v);
                }
            }
            short8 o0 = *(short8*)(us + orow*72 + oc*8);
            short8 o1 = *(short8*)(us + orow*72 + 32 + oc*8);
            ushort_t* og = (ushort_t*)Cout + (size_t)(rowBase + wm*64 + mt*16 + orow)*Nc
                           + colBase + wn*64;
            *(short8*)(og + oc*8) = o0;
            *(short8*)(og + 32 + oc*8) = o1;
        }
    }
}

// ---------------------------------------------------------------------------
// Flash attention v3: softmax 16-lane reductions via pure-VALU DPP butterfly
// (bit-exact xor-equivalents; R10 change, verified R11: -156 us total).
// LPAD 72 elements = 144 B (16B-aligned for b128).
#define LPAD 72
__global__ __launch_bounds__(256) void fattn_kernel(const ushort_t* __restrict__ QKV,
                                                    const ushort_t* __restrict__ VT,
                                                    ushort_t* __restrict__ O) {
    __shared__ __attribute__((aligned(16))) ushort_t Ks[64*LPAD];
    __shared__ __attribute__((aligned(16))) ushort_t Vs[64*LPAD];
    __shared__ __attribute__((aligned(16))) ushort_t Pw[4*16*LPAD];
    int b = blockIdx.z, h = blockIdx.y;
    int qBase = blockIdx.x * 64;
    int tid = threadIdx.x;
    int lane = tid & 63, w = tid >> 6;
    int L = lane & 15, G = lane >> 4;

    short8 qf[2];
    {
        const ushort_t* qp = QKV + ((size_t)(b*N_ + qBase + w*16 + L))*DQKV_ + h*HD_ + G*8;
        qf[0] = *(const short8*)(qp);
        qf[1] = *(const short8*)(qp + 32);
    }

    floatx4 oacc[4];
#pragma unroll
    for (int nt = 0; nt < 4; nt++) oacc[nt] = (floatx4){0.f,0.f,0.f,0.f};
    float mrow[4], lrow[4];
#pragma unroll
    for (int r = 0; r < 4; r++) { mrow[r] = -3.0e38f; lrow[r] = 0.f; }

    ushort_t* pw = Pw + w*16*LPAD;
    const ushort_t* Kbase = QKV + (size_t)b*N_*DQKV_ + D_ + h*HD_;
    const ushort_t* Vbase = VT + ((size_t)b*H_ + h)*64*N_;

    // staging map: 512 chunks (16B) per buffer; thread covers chunk tid and tid+256
    int srow = tid >> 3;         // 0..31 (and +32)
    int dc   = tid & 7;
    const ushort_t* Kg0 = Kbase + (size_t)srow*DQKV_ + dc*8;
    const ushort_t* Kg1 = Kbase + (size_t)(srow+32)*DQKV_ + dc*8;
    const ushort_t* Vg0 = Vbase + (size_t)srow*N_ + dc*8;       // srow = d-row for V
    const ushort_t* Vg1 = Vbase + (size_t)(srow+32)*N_ + dc*8;

    short8 rk0, rk1, rv0, rv1;
    rk0 = *(const short8*)(Kg0);
    rk1 = *(const short8*)(Kg1);
    rv0 = *(const short8*)(Vg0);
    rv1 = *(const short8*)(Vg1);

    for (int kt = 0; kt < N_/64; kt++) {
        __syncthreads();   // prior tile's PV reads of Ks/Vs complete
        *(short8*)(Ks + srow*LPAD + dc*8)       = rk0;
        *(short8*)(Ks + (srow+32)*LPAD + dc*8)  = rk1;
        *(short8*)(Vs + srow*LPAD + dc*8)       = rv0;
        *(short8*)(Vs + (srow+32)*LPAD + dc*8)  = rv1;
        __syncthreads();
        if (kt + 1 < N_/64) {   // prefetch next tile (in flight across compute)
            rk0 = *(const short8*)(Kg0 + (size_t)(kt+1)*64*DQKV_);
            rk1 = *(const short8*)(Kg1 + (size_t)(kt+1)*64*DQKV_);
            rv0 = *(const short8*)(Vg0 + (kt+1)*64);
            rv1 = *(const short8*)(Vg1 + (kt+1)*64);
        }

        // S = Q K^T  (16 q-rows x 64 keys per wave)
        floatx4 sc[4];
#pragma unroll
        for (int ct = 0; ct < 4; ct++) sc[ct] = (floatx4){0.f,0.f,0.f,0.f};
#pragma unroll
        for (int ks = 0; ks < 2; ks++)
#pragma unroll
            for (int ct = 0; ct < 4; ct++) {
                short8 bf = *(const short8*)(Ks + (ct*16 + L)*LPAD + ks*32 + G*8);
                sc[ct] = __builtin_amdgcn_mfma_f32_16x16x32_bf16(qf[ks], bf, sc[ct], 0, 0, 0);
            }

        // online softmax over this 64-key tile
        float rmax[4], rsum[4];
#pragma unroll
        for (int r = 0; r < 4; r++) {
#pragma unroll
            for (int ct = 0; ct < 4; ct++) sc[ct][r] *= 0.125f;
            rmax[r] = fmaxf(fmaxf(sc[0][r], sc[1][r]), fmaxf(sc[2][r], sc[3][r]));
        }
        // 16-lane max reduce via DPP (bit-exact vs shfl_xor 1,2,4,8)
#pragma unroll
        for (int r = 0; r < 4; r++) {
            rmax[r] = fmaxf(rmax[r], dpp_mov_f<0xB1>(rmax[r]));   // xor 1
            rmax[r] = fmaxf(rmax[r], dpp_mov_f<0x4E>(rmax[r]));   // xor 2
            rmax[r] = fmaxf(rmax[r], dpp_mov_f<0x141>(rmax[r]));  // xor 4 (half_mirror)
            rmax[r] = fmaxf(rmax[r], dpp_mov_f<0x140>(rmax[r]));  // xor 8 (mirror)
        }
        float corr[4];
#pragma unroll
        for (int r = 0; r < 4; r++) {
            float mn = fmaxf(mrow[r], rmax[r]);
            corr[r] = __expf(mrow[r] - mn);
            mrow[r] = mn;
            rsum[r] = 0.f;
#pragma unroll
            for (int ct = 0; ct < 4; ct++) {
                float p = __expf(sc[ct][r] - mn);
                sc[ct][r] = p;
                rsum[r] += p;
            }
        }
        // 16-lane sum reduce via DPP (bit-exact: same ascending xor order,
        // mirror levels deliver bit-identical partner values by uniformity)
#pragma unroll
        for (int r = 0; r < 4; r++) {
            rsum[r] += dpp_mov_f<0xB1>(rsum[r]);
            rsum[r] += dpp_mov_f<0x4E>(rsum[r]);
            rsum[r] += dpp_mov_f<0x141>(rsum[r]);
            rsum[r] += dpp_mov_f<0x140>(rsum[r]);
        }
#pragma unroll
        for (int r = 0; r < 4; r++) lrow[r] = lrow[r]*corr[r] + rsum[r];

        // P (C-layout) -> wave-private LDS -> A-layout (in-wave ordering, no barrier)
#pragma unroll
        for (int ct = 0; ct < 4; ct++)
#pragma unroll
            for (int r = 0; r < 4; r++)
                pw[(G*4 + r)*LPAD + ct*16 + L] = f2bf(sc[ct][r]);
#pragma unroll
        for (int nt = 0; nt < 4; nt++)
#pragma unroll
            for (int r = 0; r < 4; r++) oacc[nt][r] *= corr[r];

        // O += P V
#pragma unroll
        for (int ks = 0; ks < 2; ks++) {
            short8 pf = *(const short8*)(pw + L*LPAD + ks*32 + G*8);
#pragma unroll
            for (int nt = 0; nt < 4; nt++) {
                short8 vf = *(const short8*)(Vs + (nt*16 + L)*LPAD + ks*32 + G*8);
                oacc[nt] = __builtin_amdgcn_mfma_f32_16x16x32_bf16(pf, vf, oacc[nt], 0, 0, 0);
            }
        }
    }

    // normalized O through wave-private pw slab -> vector global store
    float inv[4];
#pragma unroll
    for (int r = 0; r < 4; r++) inv[r] = 1.0f / lrow[r];
#pragma unroll
    for (int nt = 0; nt < 4; nt++)
#pragma unroll
        for (int r = 0; r < 4; r++)
            pw[(G*4 + r)*LPAD + nt*16 + L] = f2bf(oacc[nt][r]*inv[r]);
    int orow = lane >> 2, oc = lane & 3;
    short8 o0 = *(short8*)(pw + orow*LPAD + oc*8);
    short8 o1 = *(short8*)(pw + orow*LPAD + 32 + oc*8);
    ushort_t* og = O + (size_t)(b*N_ + qBase + w*16 + orow)*D_ + h*HD_;
    *(short8*)(og + oc*8) = o0;
    *(short8*)(og + 32 + oc*8) = o1;
}

// ---------------------------------------------------------------------------
// Final projection v2: one wave per row (coalesced); pred[m,c] = X[m,:] @ pw[:,c]
__global__ __launch_bounds__(256) void proj_kernel(const float* __restrict__ X,
                                                   const float* __restrict__ pw,
                                                   float* __restrict__ pred) {
    int wid = threadIdx.x >> 6, lane = threadIdx.x & 63;
    int m = blockIdx.x*4 + wid;
    const float* xr = X + (size_t)m*D_;
    float a0 = 0.f, a1 = 0.f, a2 = 0.f;
#pragma unroll
    for (int i = 0; i < 6; i++) {
        int k = lane + i*64;
        float xv = xr[k];
        a0 += xv*pw[k*3+0]; a1 += xv*pw[k*3+1]; a2 += xv*pw[k*3+2];
    }
#pragma unroll
    for (int off = 32; off; off >>= 1) {
        a0 += __shfl_xor(a0, off, 64);
        a1 += __shfl_xor(a1, off, 64);
        a2 += __shfl_xor(a2, off, 64);
    }
    if (lane == 0) {
        pred[m*3+0] = a0; pred[m*3+1] = a1; pred[m*3+2] = a2;
    }
}

// ---------------------------------------------------------------------------
// FPS v7 (kept: 926-933 us measured floor; latency-chain-bound, 4 waves).
// 256 threads (4 waves, 1/SIMD), 32 pts/thread, packed v_pk math (bit-exact),
// LDS-buffered centers, 16-slot merge: one slot read + 4 DPP levels.
// Tie-break exact: u64 (dist_bits<<32)|~(bj*256+t), max-reduce.
template<int CTRL>
__device__ __forceinline__ u64_t dpp_max64(u64_t x) {
    unsigned lo = (unsigned)x;
    unsigned hi = (unsigned)(x >> 32);
    lo = (unsigned)__builtin_amdgcn_update_dpp((int)lo, (int)lo, CTRL, 0xF, 0xF, false);
    hi = (unsigned)__builtin_amdgcn_update_dpp((int)hi, (int)hi, CTRL, 0xF, 0xF, false);
    u64_t o = ((u64_t)hi << 32) | lo;
    return (o > x) ? o : x;
}
__device__ __forceinline__ floatx2 pk_sub(floatx2 a, floatx2 b) {
    floatx2 r;
    asm("v_pk_add_f32 %0, %1, %2 neg_lo:[0,1] neg_hi:[0,1]" : "=v"(r) : "v"(a), "v"(b));
    return r;
}
__device__ __forceinline__ floatx2 pk_mul(floatx2 a, floatx2 b) {
    floatx2 r;
    asm("v_pk_mul_f32 %0, %1, %2" : "=v"(r) : "v"(a), "v"(b));
    return r;
}
__device__ __forceinline__ floatx2 pk_add(floatx2 a, floatx2 b) {
    floatx2 r;
    asm("v_pk_add_f32 %0, %1, %2" : "=v"(r) : "v"(a), "v"(b));
    return r;
}

__global__ __launch_bounds__(256) void fps_kernel(const float* __restrict__ pts,
                                                  float* __restrict__ centers) {
    __shared__ float Lx[P_], Ly[P_], Lz[P_];            // 96 KiB
    __shared__ float Cbuf[N_*3];                        // 12 KiB (centers staging)
    __shared__ u64_t slot[2][16];
    int b = blockIdx.x, t = threadIdx.x;
    const float* pb = pts + (size_t)b*P_*3;
    floatx2 px[16], py[16], pz[16];
    float dist[32];
#pragma unroll
    for (int j = 0; j < 32; j++) {
        int p = j*256 + t;
        float x = pb[p*3+0], y = pb[p*3+1], z = pb[p*3+2];
        Lx[p] = x; Ly[p] = y; Lz[p] = z;
        px[j>>1][j&1] = x; py[j>>1][j&1] = y; pz[j>>1][j&1] = z;
        dist[j] = 1e10f;
    }
    int winner = 0;
    __syncthreads();
    for (int it = 0; it < N_; it++) {
        float lx = Lx[winner], ly = Ly[winner], lz = Lz[winner];
        if (t == 0) {
            Cbuf[it*3+0] = lx; Cbuf[it*3+1] = ly; Cbuf[it*3+2] = lz;
        }
        floatx2 lx2 = {lx, lx}, ly2 = {ly, ly}, lz2 = {lz, lz};
        // per-thread best: strict > with ascending j == smallest index on ties
        float bd = -1.0f; int bj = 0;
#pragma unroll
        for (int jj = 0; jj < 16; jj++) {
            floatx2 dx = pk_sub(px[jj], lx2);
            floatx2 dy = pk_sub(py[jj], ly2);
            floatx2 dz = pk_sub(pz[jj], lz2);
            // exact order: (dx*dx + dy*dy) + dz*dz, all RN, no contraction
            floatx2 d2 = pk_add(pk_add(pk_mul(dx,dx), pk_mul(dy,dy)), pk_mul(dz,dz));
            float d0 = fminf(dist[2*jj+0], d2[0]);
            dist[2*jj+0] = d0;
            bool g0 = d0 > bd; bd = g0 ? d0 : bd; bj = g0 ? 2*jj+0 : bj;
            float d1 = fminf(dist[2*jj+1], d2[1]);
            dist[2*jj+1] = d1;
            bool g1 = d1 > bd; bd = g1 ? d1 : bd; bj = g1 ? 2*jj+1 : bj;
        }
        // pack once: global idx p = bj*256 + t (ascending in j), ~p -> first-wins
        u64_t best = ((u64_t)__float_as_uint(bd) << 32)
                   | (unsigned)(~(unsigned)((bj<<8) + t));
        // in-row (16-lane) argmax, pure VALU
        best = dpp_max64<0xB1>(best);    // quad_perm [1,0,3,2] : xor 1
        best = dpp_max64<0x4E>(best);    // quad_perm [2,3,0,1] : xor 2
        best = dpp_max64<0x124>(best);   // row_ror:4
        best = dpp_max64<0x128>(best);   // row_ror:8
        int par = it & 1;
        if ((t & 15) == 0) slot[par][t >> 4] = best;   // 16 row maxima (4 waves x 4 rows)
        __syncthreads();
        // cross-row merge: one slot per lane, 4 DPP levels -> global max in all lanes
        u64_t v = slot[par][t & 15];
        v = dpp_max64<0xB1>(v);
        v = dpp_max64<0x4E>(v);
        v = dpp_max64<0x124>(v);
        v = dpp_max64<0x128>(v);
        winner = (int)(~(unsigned)(v & 0xFFFFFFFFull));
    }
    __syncthreads();
    // coalesced centers flush (3072 floats, 12 per thread)
    float* cb = centers + (size_t)b*N_*3;
#pragma unroll
    for (int i = 0; i < 12; i++) cb[t + i*256] = Cbuf[t + i*256];
}

// ---------------------------------------------------------------------------
__global__ __launch_bounds__(256) void nnmin_kernel(const float* __restrict__ Asrc,
                                                    const float* __restrict__ Bsrc,
                                                    float* __restrict__ outmin) {
    int b = blockIdx.y;
    int i = blockIdx.x*256 + threadIdx.x;
    __shared__ float tile[256][3];
    const float* ar = Asrc + ((size_t)b*N_ + i)*3;
    float ax = ar[0], ay = ar[1], az = ar[2];
    float best = 3.0e38f;
    for (int j0 = 0; j0 < N_; j0 += 256) {
        __syncthreads();
        const float* br = Bsrc + ((size_t)b*N_ + j0 + threadIdx.x)*3;
        tile[threadIdx.x][0] = br[0]; tile[threadIdx.x][1] = br[1]; tile[threadIdx.x][2] = br[2];
        __syncthreads();
        for (int j = 0; j < 256; j++) {
            float dx = ax - tile[j][0], dy = ay - tile[j][1], dz = az - tile[j][2];
            float d = dx*dx + dy*dy + dz*dz;
            best = fminf(best, d);
        }
    }
    outmin[(size_t)b*N_ + i] = sqrtf(best);
}

__global__ __launch_bounds__(256) void knn_kernel(const float* __restrict__ Pp,
                                                  float* __restrict__ mean_d) {
    int b = blockIdx.y;
    int i = blockIdx.x*256 + threadIdx.x;
    __shared__ float tile[256][3];
    const float* ar = Pp + ((size_t)b*N_ + i)*3;
    float ax = ar[0], ay = ar[1], az = ar[2];
    float s[6];
#pragma unroll
    for (int q = 0; q < 6; q++) s[q] = 3.0e38f;
    for (int j0 = 0; j0 < N_; j0 += 256) {
        __syncthreads();
        const float* br = Pp + ((size_t)b*N_ + j0 + threadIdx.x)*3;
        tile[threadIdx.x][0] = br[0]; tile[threadIdx.x][1] = br[1]; tile[threadIdx.x][2] = br[2];
        __syncthreads();
        for (int j = 0; j < 256; j++) {
            float dx = ax - tile[j][0], dy = ay - tile[j][1], dz = az - tile[j][2];
            float d = dx*dx + dy*dy + dz*dz;
            if (d < s[5]) {
                s[5] = d;
#pragma unroll
                for (int q = 5; q > 0; q--)
                    if (s[q] < s[q-1]) { float tmp = s[q]; s[q] = s[q-1]; s[q-1] = tmp; }
            }
        }
    }
    float msum = sqrtf(s[1]) + sqrtf(s[2]) + sqrtf(s[3]) + sqrtf(s[4]) + sqrtf(s[5]);
    mean_d[(size_t)b*N_ + i] = msum * 0.2f;
}

__global__ __launch_bounds__(256) void kl_kernel(const float* __restrict__ md,
                                                 float* __restrict__ klb) {
    int b = blockIdx.x, t = threadIdx.x;
    const float* row = md + (size_t)b*N_;
    float v[4];
#pragma unroll
    for (int i = 0; i < 4; i++) v[i] = row[t + i*256];
    float mx = fmaxf(fmaxf(v[0], v[1]), fmaxf(v[2], v[3]));
#pragma unroll
    for (int off = 32; off; off >>= 1) mx = fmaxf(mx, __shfl_xor(mx, off, 64));
    __shared__ float redm[4], rse[4], rsx[4];
    int wid = t >> 6, lane = t & 63;
    if (lane == 0) redm[wid] = mx;
    __syncthreads();
    mx = fmaxf(fmaxf(redm[0], redm[1]), fmaxf(redm[2], redm[3]));
    float se = 0.f, sx = 0.f;
#pragma unroll
    for (int i = 0; i < 4; i++) { se += expf(v[i]-mx); sx += v[i]; }
#pragma unroll
    for (int off = 32; off; off >>= 1) { se += __shfl_xor(se, off, 64); sx += __shfl_xor(sx, off, 64); }
    if (lane == 0) { rse[wid] = se; rsx[wid] = sx; }
    __syncthreads();
    if (t == 0) {
        float SE = rse[0]+rse[1]+rse[2]+rse[3];
        float SX = rsx[0]+rsx[1]+rsx[2]+rsx[3];
        klb[b] = mx + logf(SE) - SX*(1.0f/(float)N_) - logf((float)N_);
    }
}

__global__ __launch_bounds__(256) void final_kernel(const float* __restrict__ rma,
                                                    const float* __restrict__ rmb,
                                                    const float* __restrict__ klb,
                                                    float* __restrict__ out) {
    int t = threadIdx.x;
    float s = 0.f;
    for (int i = t; i < B_*N_; i += 256) s += rma[i] + rmb[i];
#pragma unroll
    for (int off = 32; off; off >>= 1) s += __shfl_xor(s, off, 64);
    __shared__ float red[4];
    int wid = t >> 6, lane = t & 63;
    if (lane == 0) red[wid] = s;
    __syncthreads();
    if (t == 0) {
        float S = red[0]+red[1]+red[2]+red[3];
        out[0] = 0.5f*S/(float)(B_*N_);
        out[1] = 0.f;
        float K = 0.f;
        for (int b = 0; b < B_; b++) K += klb[b];
        out[1] = K/(float)B_;
    }
}

// ---------------------------------------------------------------------------
extern "C" void kernel_launch(void* const* d_in, const int* in_sizes, int n_in,
                              void* d_out, int out_size, void* d_ws, size_t ws_size,
                              hipStream_t stream) {
    (void)in_sizes; (void)n_in; (void)out_size; (void)ws_size;
    const float* pts     = (const float*)d_in[0];
    const float* grid    = (const float*)d_in[1];
    const float* embed_w = (const float*)d_in[2];
    const float* proj_w  = (const float*)d_in[3];
    const float* ln1_w   = (const float*)d_in[4];
    const float* ln1_b   = (const float*)d_in[5];
    const float* qkv_w   = (const float*)d_in[6];
    const float* qkv_b   = (const float*)d_in[7];
    const float* attn_w  = (const float*)d_in[8];
    const float* attn_b  = (const float*)d_in[9];
    const float* ln2_w   = (const float*)d_in[10];
    const float* ln2_b   = (const float*)d_in[11];
    const float* mlp_w1  = (const float*)d_in[12];
    const float* mlp_b1  = (const float*)d_in[13];
    const float* mlp_w2  = (const float*)d_in[14];
    const float* mlp_b2  = (const float*)d_in[15];
    float* out = (float*)d_out;

    // workspace layout (~144 MB)
    float*    X     = (float*)d_ws;                         // M*D f32
    ushort_t* Hb16  = (ushort_t*)(X + (size_t)M_*D_);       // M*D bf16
    ushort_t* BIG16 = Hb16 + (size_t)M_*D_;                 // M*1536 bf16 (QKV / MLP hidden)
    ushort_t* VT    = BIG16 + (size_t)M_*DH_;               // B*H*64*N bf16 (V transposed)
    ushort_t* WQ    = VT  + (size_t)B_*H_*HD_*N_;           // L*1152*384
    ushort_t* WA    = WQ  + (size_t)L_*DQKV_*D_;            // L*384*384
    ushort_t* WM1   = WA  + (size_t)L_*D_*D_;               // L*1536*384
    ushort_t* WM2   = WM1 + (size_t)L_*DH_*D_;              // L*384*1536
    float*    PRED  = (float*)(WM2 + (size_t)L_*D_*DH_);    // M*3
    float*    CENT  = PRED + (size_t)M_*3;                  // B*N*3
    float*    RMA   = CENT + (size_t)B_*N_*3;               // B*N
    float*    RMB   = RMA  + (size_t)B_*N_;                 // B*N
    float*    MEAND = RMB  + (size_t)B_*N_;                 // B*N
    float*    KLB   = MEAND + (size_t)B_*N_;                // B

    // one-time weight transpose-casts (f32 [K,N] -> bf16 [N,K])
    transcast_kernel<<<dim3(DQKV_/32, D_/32,  L_), 256, 0, stream>>>(qkv_w,  WQ,  D_,  DQKV_);
    transcast_kernel<<<dim3(D_/32,    D_/32,  L_), 256, 0, stream>>>(attn_w, WA,  D_,  D_);
    transcast_kernel<<<dim3(DH_/32,   D_/32,  L_), 256, 0, stream>>>(mlp_w1, WM1, D_,  DH_);
    transcast_kernel<<<dim3(D_/32,    DH_/32, L_), 256, 0, stream>>>(mlp_w2, WM2, DH_, D_);

    // FPS (independent of transformer)
    fps_kernel<<<B_, 256, 0, stream>>>(pts, CENT);

    embed_kernel<<<M_, D_, 0, stream>>>(grid, embed_w, X);

    for (int l = 0; l < L_; l++) {
        ln_kernel<<<M_/4, 256, 0, stream>>>(X, ln1_w + l*D_, ln1_b + l*D_, Hb16);
        mfma_gemm<3><<<dim3(DQKV_/128, M_/128), 256, 0, stream>>>(
            Hb16, WQ + (size_t)l*DQKV_*D_, qkv_b + l*DQKV_, BIG16, VT, D_, DQKV_);
        fattn_kernel<<<dim3(N_/64, H_, B_), 256, 0, stream>>>(BIG16, VT, Hb16);
        mfma_gemm<1><<<dim3(D_/128, M_/128), 256, 0, stream>>>(
            Hb16, WA + (size_t)l*D_*D_, attn_b + l*D_, X, nullptr, D_, D_);
        ln_kernel<<<M_/4, 256, 0, stream>>>(X, ln2_w + l*D_, ln2_b + l*D_, Hb16);
        mfma_gemm<2><<<dim3(DH_/128, M_/128), 256, 0, stream>>>(
            Hb16, WM1 + (size_t)l*DH_*D_, mlp_b1 + l*DH_, BIG16, nullptr, D_, DH_);
        mfma_gemm<1><<<dim3(D_/128, M_/128), 256, 0, stream>>>(
            BIG16, WM2 + (size_t)l*D_*DH_, mlp_b2 + l*D_, X, nullptr, DH_, D_);
    }

    proj_kernel<<<M_/4, 256, 0, stream>>>(X, proj_w, PRED);

    nnmin_kernel<<<dim3(N_/256, B_), 256, 0, stream>>>(PRED, CENT, RMA);
    nnmin_kernel<<<dim3(N_/256, B_), 256, 0, stream>>>(CENT, PRED, RMB);
    knn_kernel<<<dim3(N_/256, B_), 256, 0, stream>>>(PRED, MEAND);
    kl_kernel<<<B_, 256, 0, stream>>>(MEAND, KLB);
    final_kernel<<<1, 256, 0, stream>>>(RMA, RMB, KLB, out);
}